// Round 10
// baseline (394.802 us; speedup 1.0000x reference)
//
#include <hip/hip_runtime.h>
#include <hip/hip_bf16.h>
#include <math.h>

#define S_LEN 1024
#define HIDN  1024
#define NHEAD 16
#define HDIM  64
#define BATCH 4
#define MTOT  (BATCH * S_LEN)   // 4096

typedef __attribute__((ext_vector_type(8))) short          bf16v8;
typedef __attribute__((ext_vector_type(8))) unsigned short u16v8;
typedef __attribute__((ext_vector_type(4))) unsigned short u16v4;
typedef __attribute__((ext_vector_type(4))) float          f32v4;

// ---------------------------------------------------------------------------
// bf16 hi/lo split helpers (RNE)
// ---------------------------------------------------------------------------
__device__ __forceinline__ unsigned short f2bf_rne(float x) {
    unsigned int u = __float_as_uint(x);
    unsigned int r = (u + 0x7fffu + ((u >> 16) & 1u)) >> 16;
    return (unsigned short)r;
}
__device__ __forceinline__ float bf2f(unsigned short h) {
    return __uint_as_float(((unsigned int)h) << 16);
}
__device__ __forceinline__ void split2(float x, unsigned short& h, unsigned short& l) {
    h = f2bf_rne(x);
    l = f2bf_rne(x - bf2f(h));
}

// ---------------------------------------------------------------------------
// split_w4: z-batched weight split. W f32 [K][N] -> transposed hi/lo [N][K].
// ---------------------------------------------------------------------------
__global__ __launch_bounds__(256) void split_w4(
    const float* __restrict__ W0, const float* __restrict__ W1,
    const float* __restrict__ W2, const float* __restrict__ W3,
    unsigned short* __restrict__ Hbase, unsigned short* __restrict__ Lbase)
{
    __shared__ float T[64][65];
    const int t  = threadIdx.x;
    const int k0 = blockIdx.y * 64;
    const int n0 = blockIdx.x * 64;
    const int z  = blockIdx.z;
    const float* W = (z == 0) ? W0 : (z == 1) ? W1 : (z == 2) ? W2 : W3;
    unsigned short* H = Hbase + (size_t)z * 1024 * 1024;
    unsigned short* L = Lbase + (size_t)z * 1024 * 1024;

    const int r = t >> 4;
    const int c = (t & 15) * 4;
#pragma unroll
    for (int i = 0; i < 4; ++i) {
        const int rr = r + i * 16;
        const float4 v = *(const float4*)&W[(size_t)(k0 + rr) * 1024 + n0 + c];
        T[rr][c + 0] = v.x; T[rr][c + 1] = v.y;
        T[rr][c + 2] = v.z; T[rr][c + 3] = v.w;
    }
    __syncthreads();

    const int n  = t >> 2;
    const int ko = (t & 3) * 16;
    u16v8 h0, h1, l0, l1;
#pragma unroll
    for (int kk = 0; kk < 8; ++kk) {
        unsigned short hh, ll;
        split2(T[ko + kk][n], hh, ll);
        h0[kk] = hh; l0[kk] = ll;
    }
#pragma unroll
    for (int kk = 0; kk < 8; ++kk) {
        unsigned short hh, ll;
        split2(T[ko + 8 + kk][n], hh, ll);
        h1[kk] = hh; l1[kk] = ll;
    }
    unsigned short* Hp = &H[(size_t)(n0 + n) * 1024 + k0 + ko];
    unsigned short* Lp = &L[(size_t)(n0 + n) * 1024 + k0 + ko];
    *(u16v8*)(Hp)     = h0;
    *(u16v8*)(Hp + 8) = h1;
    *(u16v8*)(Lp)     = l0;
    *(u16v8*)(Lp + 8) = l1;
}

// ---------------------------------------------------------------------------
// bqp[n] = sum_k bq[k]*Wp[k][n] + bp[n]
// ---------------------------------------------------------------------------
__global__ __launch_bounds__(256) void bqp_kernel(
    const float* __restrict__ bq, const float* __restrict__ Wp,
    const float* __restrict__ bp, float* __restrict__ bqp)
{
    __shared__ float red[4][64];
    const int t  = threadIdx.x;
    const int n0 = blockIdx.x * 64;
    const int nn = t & 63;
    const int ch = t >> 6;
    float s = 0.f;
    for (int k = ch * 256; k < ch * 256 + 256; ++k)
        s = fmaf(bq[k], Wp[(size_t)k * 1024 + n0 + nn], s);
    red[ch][nn] = s;
    __syncthreads();
    if (t < 64)
        bqp[n0 + nn] = red[0][nn] + red[1][nn] + red[2][nn] + red[3][nn] + bp[n0 + nn];
}

// ---------------------------------------------------------------------------
// alpha = sigmoid(query @ Wus + bus)   [MTOT,16]
// ---------------------------------------------------------------------------
__global__ __launch_bounds__(256) void alpha_kernel(
    const float* __restrict__ X, const float* __restrict__ Wus,
    const float* __restrict__ bus, float* __restrict__ alpha)
{
    __shared__ float Ws[1024 * 16];
    const int t = threadIdx.x;
#pragma unroll
    for (int i = 0; i < 16; ++i) {
        const int idx = t + i * 256;
        *reinterpret_cast<float4*>(&Ws[idx * 4]) =
            *reinterpret_cast<const float4*>(&Wus[idx * 4]);
    }
    __syncthreads();

    const int r = t >> 4, c = t & 15;
    const size_t row = (size_t)blockIdx.x * 16 + r;
    const float* x = &X[row * 1024];
    float acc = 0.f;
    for (int kk = 0; kk < 1024; kk += 4) {
        const float4 xv = *reinterpret_cast<const float4*>(&x[kk]);
        acc = fmaf(xv.x, Ws[(kk + 0) * 16 + c], acc);
        acc = fmaf(xv.y, Ws[(kk + 1) * 16 + c], acc);
        acc = fmaf(xv.z, Ws[(kk + 2) * 16 + c], acc);
        acc = fmaf(xv.w, Ws[(kk + 3) * 16 + c], acc);
    }
    acc += bus[c];
    alpha[row * 16 + c] = 1.f / (1.f + expf(-acc));
}

// ---------------------------------------------------------------------------
// Templated bf16x3 MFMA GEMM (proven core). BM=128, BN=64, BK=32, 512 thr,
// launch_bounds(512,2). AF32: A raw f32 inline-split. EPI: 0=f32 out,
// 4=full-transpose bf16 hi/lo out (for Wqp), no bias.
// ---------------------------------------------------------------------------
template<int AF32, int EPI>
__global__ __launch_bounds__(512, 2) void gemm_t(
    const float* __restrict__ Af,
    const unsigned short* __restrict__ Ah, const unsigned short* __restrict__ Al,
    const unsigned short* __restrict__ Bh, const unsigned short* __restrict__ Bl,
    const float* __restrict__ bias, float* __restrict__ Cf,
    unsigned short* __restrict__ Ch, unsigned short* __restrict__ Cl)
{
    __shared__ short Ash[128][40];
    __shared__ short Asl[128][40];
    __shared__ short Bsh[64][40];
    __shared__ short Bsl[64][40];

    const int t    = threadIdx.x;
    const int bm   = blockIdx.y * 128;
    const int bn   = blockIdx.x * 64;
    const int lane = t & 63;
    const int wid  = t >> 6;
    const int wr   = wid >> 1;
    const int wc   = wid & 1;
    const int fr   = lane & 15;
    const int fq   = lane >> 4;
    const int ks   = fq * 8;

    f32v4 zero = {0.f, 0.f, 0.f, 0.f};
    f32v4 acc[2][2];
#pragma unroll
    for (int i = 0; i < 2; ++i)
#pragma unroll
        for (int j = 0; j < 2; ++j) acc[i][j] = zero;

    const int sra = t >> 2;
    const int sca = (t & 3) * 8;
    const int tb  = t & 255;
    const int srb = tb >> 2;
    const int scb = (tb & 3) * 8;
    const bool isBl = (t >= 256);
    const unsigned short* pB = isBl ? &Bl[(size_t)(bn + srb) * 1024 + scb]
                                    : &Bh[(size_t)(bn + srb) * 1024 + scb];
    const float* pAf = AF32 ? &Af[(size_t)(bm + sra) * 1024 + sca] : nullptr;
    const unsigned short* pAh = AF32 ? nullptr : &Ah[(size_t)(bm + sra) * 1024 + sca];
    const unsigned short* pAl = AF32 ? nullptr : &Al[(size_t)(bm + sra) * 1024 + sca];

    u16v8 rah, ral, rb;
    auto LOAD = [&](int k0) {
        if (AF32) {
            const float4 a0 = *(const float4*)(pAf + k0);
            const float4 a1 = *(const float4*)(pAf + k0 + 4);
            const float xs[8] = {a0.x, a0.y, a0.z, a0.w, a1.x, a1.y, a1.z, a1.w};
#pragma unroll
            for (int e = 0; e < 8; ++e) {
                unsigned short hh, ll;
                split2(xs[e], hh, ll);
                rah[e] = hh; ral[e] = ll;
            }
        } else {
            rah = *(const u16v8*)(pAh + k0);
            ral = *(const u16v8*)(pAl + k0);
        }
        rb = *(const u16v8*)(pB + k0);
    };

    LOAD(0);
    for (int k0 = 0; k0 < 1024; k0 += 32) {
        __syncthreads();
        *(u16v8*)&Ash[sra][sca] = rah;
        *(u16v8*)&Asl[sra][sca] = ral;
        if (isBl) *(u16v8*)&Bsl[srb][scb] = rb;
        else      *(u16v8*)&Bsh[srb][scb] = rb;
        __syncthreads();

        if (k0 + 32 < 1024) LOAD(k0 + 32);

        bf16v8 fah[2], fal[2], fbh[2], fbl[2];
#pragma unroll
        for (int i = 0; i < 2; ++i) {
            fah[i] = *(const bf16v8*)&Ash[wr * 32 + i * 16 + fr][ks];
            fal[i] = *(const bf16v8*)&Asl[wr * 32 + i * 16 + fr][ks];
        }
#pragma unroll
        for (int j = 0; j < 2; ++j) {
            fbh[j] = *(const bf16v8*)&Bsh[wc * 32 + j * 16 + fr][ks];
            fbl[j] = *(const bf16v8*)&Bsl[wc * 32 + j * 16 + fr][ks];
        }
#pragma unroll
        for (int i = 0; i < 2; ++i)
#pragma unroll
            for (int j = 0; j < 2; ++j) {
                acc[i][j] = __builtin_amdgcn_mfma_f32_16x16x32_bf16(
                    fah[i], fbh[j], acc[i][j], 0, 0, 0);
                acc[i][j] = __builtin_amdgcn_mfma_f32_16x16x32_bf16(
                    fah[i], fbl[j], acc[i][j], 0, 0, 0);
                acc[i][j] = __builtin_amdgcn_mfma_f32_16x16x32_bf16(
                    fal[i], fbh[j], acc[i][j], 0, 0, 0);
            }
    }

#pragma unroll
    for (int j = 0; j < 2; ++j) {
        const int col = bn + wc * 32 + j * 16 + fr;
        const float bb = (EPI == 4) ? 0.f : bias[col];
#pragma unroll
        for (int i = 0; i < 2; ++i) {
            const int row0 = bm + wr * 32 + i * 16 + fq * 4;
            const f32v4 cv = acc[i][j];
            if (EPI == 4) {
                u16v4 h4, l4;
#pragma unroll
                for (int r = 0; r < 4; ++r) {
                    unsigned short hh, ll;
                    split2(cv[r], hh, ll);
                    h4[r] = hh; l4[r] = ll;
                }
                const size_t base = (size_t)col * 1024 + row0;
                *(u16v4*)&Ch[base] = h4;
                *(u16v4*)&Cl[base] = l4;
            } else {
#pragma unroll
                for (int r = 0; r < 4; ++r)
                    Cf[(size_t)(row0 + r) * 1024 + col] = cv[r] + bb;
            }
        }
    }
}

// ---------------------------------------------------------------------------
// gemm_batched: z-batched projections from raw f32 inputs (AF32 inline split).
//   z=0: q = query@Wq+bq   -> qh/ql (bf16 hi/lo)
//   z=1: k = key@Wk+bk     -> kh/kl
//   z=2: v = value@Wv+bv   -> vTh/vTl (per-head transposed)
//   z=3: p = query@Wqp+bqp -> fused posparam -> cen/c0 (p never materialized)
// ---------------------------------------------------------------------------
__global__ __launch_bounds__(512, 2) void gemm_batched(
    const float* __restrict__ query, const float* __restrict__ key_,
    const float* __restrict__ value,
    const unsigned short* __restrict__ wh, const unsigned short* __restrict__ wl,
    const unsigned short* __restrict__ w5h, const unsigned short* __restrict__ w5l,
    const float* __restrict__ bq, const float* __restrict__ bk,
    const float* __restrict__ bv, const float* __restrict__ bqp,
    unsigned short* __restrict__ qh, unsigned short* __restrict__ ql,
    unsigned short* __restrict__ kh, unsigned short* __restrict__ kl,
    unsigned short* __restrict__ vTh, unsigned short* __restrict__ vTl,
    const float* __restrict__ Wup, const float* __restrict__ Wud,
    const float* __restrict__ bup, const float* __restrict__ bud,
    const float* __restrict__ alpha, float* __restrict__ cenp,
    float* __restrict__ c0p)
{
    __shared__ short Ash[128][40];
    __shared__ short Asl[128][40];
    __shared__ short Bsh[64][40];
    __shared__ short Bsl[64][40];
    __shared__ float PSUP[2][128], PSUD[2][128];

    const int z    = blockIdx.z;
    const float* Af = (z == 0 || z == 3) ? query : (z == 1) ? key_ : value;
    const unsigned short* Bh = (z < 3) ? wh + (size_t)z * 1024 * 1024 : w5h;
    const unsigned short* Bl = (z < 3) ? wl + (size_t)z * 1024 * 1024 : w5l;
    const float* bias = (z == 0) ? bq : (z == 1) ? bk : (z == 2) ? bv : bqp;

    const int t    = threadIdx.x;
    const int bm   = blockIdx.y * 128;
    const int bn   = blockIdx.x * 64;
    const int lane = t & 63;
    const int wid  = t >> 6;
    const int wr   = wid >> 1;
    const int wc   = wid & 1;
    const int fr   = lane & 15;
    const int fq   = lane >> 4;
    const int ks   = fq * 8;

    f32v4 zero = {0.f, 0.f, 0.f, 0.f};
    f32v4 acc[2][2];
#pragma unroll
    for (int i = 0; i < 2; ++i)
#pragma unroll
        for (int j = 0; j < 2; ++j) acc[i][j] = zero;

    const int sra = t >> 2;
    const int sca = (t & 3) * 8;
    const int tb  = t & 255;
    const int srb = tb >> 2;
    const int scb = (tb & 3) * 8;
    const bool isBl = (t >= 256);
    const unsigned short* pB = isBl ? &Bl[(size_t)(bn + srb) * 1024 + scb]
                                    : &Bh[(size_t)(bn + srb) * 1024 + scb];
    const float* pAf = &Af[(size_t)(bm + sra) * 1024 + sca];

    u16v8 rah, ral, rb;
    auto LOAD = [&](int k0) {
        const float4 a0 = *(const float4*)(pAf + k0);
        const float4 a1 = *(const float4*)(pAf + k0 + 4);
        const float xs[8] = {a0.x, a0.y, a0.z, a0.w, a1.x, a1.y, a1.z, a1.w};
#pragma unroll
        for (int e = 0; e < 8; ++e) {
            unsigned short hh, ll;
            split2(xs[e], hh, ll);
            rah[e] = hh; ral[e] = ll;
        }
        rb = *(const u16v8*)(pB + k0);
    };

    LOAD(0);
    for (int k0 = 0; k0 < 1024; k0 += 32) {
        __syncthreads();
        *(u16v8*)&Ash[sra][sca] = rah;
        *(u16v8*)&Asl[sra][sca] = ral;
        if (isBl) *(u16v8*)&Bsl[srb][scb] = rb;
        else      *(u16v8*)&Bsh[srb][scb] = rb;
        __syncthreads();

        if (k0 + 32 < 1024) LOAD(k0 + 32);

        bf16v8 fah[2], fal[2], fbh[2], fbl[2];
#pragma unroll
        for (int i = 0; i < 2; ++i) {
            fah[i] = *(const bf16v8*)&Ash[wr * 32 + i * 16 + fr][ks];
            fal[i] = *(const bf16v8*)&Asl[wr * 32 + i * 16 + fr][ks];
        }
#pragma unroll
        for (int j = 0; j < 2; ++j) {
            fbh[j] = *(const bf16v8*)&Bsh[wc * 32 + j * 16 + fr][ks];
            fbl[j] = *(const bf16v8*)&Bsl[wc * 32 + j * 16 + fr][ks];
        }
#pragma unroll
        for (int i = 0; i < 2; ++i)
#pragma unroll
            for (int j = 0; j < 2; ++j) {
                acc[i][j] = __builtin_amdgcn_mfma_f32_16x16x32_bf16(
                    fah[i], fbh[j], acc[i][j], 0, 0, 0);
                acc[i][j] = __builtin_amdgcn_mfma_f32_16x16x32_bf16(
                    fah[i], fbl[j], acc[i][j], 0, 0, 0);
                acc[i][j] = __builtin_amdgcn_mfma_f32_16x16x32_bf16(
                    fal[i], fbh[j], acc[i][j], 0, 0, 0);
            }
    }

    if (z == 3) {
        // fused posparam epilogue
        float wupj[2], wudj[2], bb[2];
#pragma unroll
        for (int j = 0; j < 2; ++j) {
            const int colL = wc * 32 + j * 16 + fr;
            wupj[j] = Wup[colL];
            wudj[j] = Wud[colL];
            bb[j]   = bias[bn + colL];
        }
        float su[2][4], sd[2][4];
#pragma unroll
        for (int i = 0; i < 2; ++i)
#pragma unroll
            for (int r = 0; r < 4; ++r) { su[i][r] = 0.f; sd[i][r] = 0.f; }
#pragma unroll
        for (int j = 0; j < 2; ++j)
#pragma unroll
            for (int i = 0; i < 2; ++i)
#pragma unroll
                for (int r = 0; r < 4; ++r) {
                    const float tv = tanhf(acc[i][j][r] + bb[j]);
                    su[i][r] = fmaf(tv, wupj[j], su[i][r]);
                    sd[i][r] = fmaf(tv, wudj[j], sd[i][r]);
                }
#pragma unroll
        for (int i = 0; i < 2; ++i)
#pragma unroll
            for (int r = 0; r < 4; ++r) {
                float a = su[i][r], d = sd[i][r];
                a += __shfl_xor(a, 1); d += __shfl_xor(d, 1);
                a += __shfl_xor(a, 2); d += __shfl_xor(d, 2);
                a += __shfl_xor(a, 4); d += __shfl_xor(d, 4);
                a += __shfl_xor(a, 8); d += __shfl_xor(d, 8);
                if (fr == 0) {
                    const int row = wr * 32 + i * 16 + fq * 4 + r;
                    PSUP[wc][row] = a;
                    PSUD[wc][row] = d;
                }
            }
        __syncthreads();
        if (t < 128) {
            const float ap = PSUP[0][t] + PSUP[1][t] + bup[0];
            const float az = PSUD[0][t] + PSUD[1][t] + bud[0];
            const float cenv = 1024.f / (1.f + expf(-ap));
            const float win  = 1024.f / (1.f + expf(-az));
            const int grow = bm + t;
            const int hd   = bn >> 6;
            const int zz   = (grow >> 10) * 16 + hd;
            const int s    = grow & 1023;
            const float al = alpha[(size_t)grow * 16 + hd];
            cenp[(size_t)zz * 1024 + s] = cenv;
            c0p[(size_t)zz * 1024 + s]  = al * 2.f / (win * win);
        }
        return;
    }

    unsigned short* Ch = (z == 0) ? qh : (z == 1) ? kh : vTh;
    unsigned short* Cl = (z == 0) ? ql : (z == 1) ? kl : vTl;

#pragma unroll
    for (int j = 0; j < 2; ++j) {
        const int col = bn + wc * 32 + j * 16 + fr;
        const float bb = bias[col];
#pragma unroll
        for (int i = 0; i < 2; ++i) {
            const int row0 = bm + wr * 32 + i * 16 + fq * 4;
            const f32v4 cv = acc[i][j];
            if (z == 2) {
                u16v4 h4, l4;
#pragma unroll
                for (int r = 0; r < 4; ++r) {
                    unsigned short hh, ll;
                    split2(cv[r] + bb, hh, ll);
                    h4[r] = hh; l4[r] = ll;
                }
                const size_t base =
                    ((size_t)((row0 >> 10) * 16 + (col >> 6)) * 64 + (col & 63)) * 1024
                    + (row0 & 1023);
                *(u16v4*)&Ch[base] = h4;
                *(u16v4*)&Cl[base] = l4;
            } else {
#pragma unroll
                for (int r = 0; r < 4; ++r) {
                    unsigned short hh, ll;
                    split2(cv[r] + bb, hh, ll);
                    const size_t idx = (size_t)(row0 + r) * 1024 + col;
                    Ch[idx] = hh; Cl[idx] = ll;
                }
            }
        }
    }
}

// ---------------------------------------------------------------------------
// attn_fused v6: r9 structure + pass-A K double-buffer (into idle VH/VL,
// 1 barrier/tile) + s_setprio around MFMA clusters.
// ---------------------------------------------------------------------------
#define M0_SHIFT 8.0f
__global__ __launch_bounds__(512, 2) void attn_fused(
    const unsigned short* __restrict__ qh, const unsigned short* __restrict__ ql,
    const unsigned short* __restrict__ kh, const unsigned short* __restrict__ kl,
    const unsigned short* __restrict__ vTh, const unsigned short* __restrict__ vTl,
    const float* __restrict__ cen, const float* __restrict__ c0,
    float* __restrict__ attn,
    unsigned short* __restrict__ oh, unsigned short* __restrict__ ol)
{
    __shared__ unsigned short KH[64][64], KL[64][64];
    __shared__ unsigned short VH[64][64], VL[64][64];
    __shared__ unsigned short PH[128][64], PL[128][64];
    __shared__ float CEN[128], C0S[128];
    __shared__ float LSUM[2][128];
    __shared__ float RINV[128];

    const int bid   = blockIdx.x;
    const int z     = ((bid >> 6) << 3) | (bid & 7);
    const int itile = (bid >> 3) & 7;
    const int i0    = itile * 128;
    const int bq    = z >> 4;
    const int hd    = z & 15;

    const int t    = threadIdx.x;
    const int lane = t & 63;
    const int wid  = t >> 6;
    const int wrp  = wid >> 1;
    const int wc   = wid & 1;
    const int fr   = lane & 15, fq = lane >> 4;

    if (t < 128) {
        CEN[t] = cen[(size_t)z * 1024 + i0 + t];
        C0S[t] = c0[(size_t)z * 1024 + i0 + t];
    }

    bf16v8 qfh_[2][2], qfl_[2][2];
#pragma unroll
    for (int i = 0; i < 2; ++i)
#pragma unroll
        for (int kk = 0; kk < 2; ++kk) {
            const size_t qa = (size_t)(bq * 1024 + i0 + wrp * 32 + i * 16 + fr) * 1024
                              + hd * 64 + kk * 32 + fq * 8;
            qfh_[i][kk] = *(const bf16v8*)&qh[qa];
            qfl_[i][kk] = *(const bf16v8*)&ql[qa];
        }

    float lsum[2][4];
#pragma unroll
    for (int i = 0; i < 2; ++i)
#pragma unroll
        for (int r = 0; r < 4; ++r) lsum[i][r] = 0.f;

    const f32v4 zero = {0.f, 0.f, 0.f, 0.f};

    const int srow = t >> 3;
    const int sseg = t & 7;
    const int ssl  = (sseg ^ (srow & 7)) * 8;
    const unsigned short* vhb = vTh + (size_t)z * 64 * 1024;
    const unsigned short* vlb = vTl + (size_t)z * 64 * 1024;

    u16v8 rkh, rkl, rvh, rvl;
    auto LOADK = [&](int j0) {
        const size_t ga = (size_t)(bq * 1024 + j0 + srow) * 1024 + hd * 64 + sseg * 8;
        rkh = *(const u16v8*)&kh[ga];
        rkl = *(const u16v8*)&kl[ga];
    };
    auto LOADV = [&](int j0) {
        const size_t va = (size_t)srow * 1024 + j0 + sseg * 8;
        rvh = *(const u16v8*)&vhb[va];
        rvl = *(const u16v8*)&vlb[va];
    };

    // ---------------- PASS A: K double-buffered (KH/KL <-> VH/VL) ----------
    LOADK(0);
    for (int jt = 0; jt < 16; ++jt) {
        const int j0 = jt * 64;
        unsigned short (*KHc)[64] = (jt & 1) ? VH : KH;
        unsigned short (*KLc)[64] = (jt & 1) ? VL : KL;
        *(u16v8*)&KHc[srow][ssl] = rkh;
        *(u16v8*)&KLc[srow][ssl] = rkl;
        __syncthreads();
        if (jt < 15) LOADK(j0 + 64);

        f32v4 acc[2][2];
#pragma unroll
        for (int i = 0; i < 2; ++i)
#pragma unroll
            for (int j2 = 0; j2 < 2; ++j2) acc[i][j2] = zero;

        __builtin_amdgcn_s_setprio(1);
#pragma unroll
        for (int kk = 0; kk < 2; ++kk) {
            bf16v8 fbh[2], fbl[2];
#pragma unroll
            for (int j2 = 0; j2 < 2; ++j2) {
                const int rb = wc * 32 + j2 * 16 + fr;
                const int sb = ((kk * 4 + fq) ^ (rb & 7)) * 8;
                fbh[j2] = *(const bf16v8*)&KHc[rb][sb];
                fbl[j2] = *(const bf16v8*)&KLc[rb][sb];
            }
#pragma unroll
            for (int i = 0; i < 2; ++i)
#pragma unroll
                for (int j2 = 0; j2 < 2; ++j2) {
                    acc[i][j2] = __builtin_amdgcn_mfma_f32_16x16x32_bf16(
                        qfh_[i][kk], fbh[j2], acc[i][j2], 0, 0, 0);
                    acc[i][j2] = __builtin_amdgcn_mfma_f32_16x16x32_bf16(
                        qfh_[i][kk], fbl[j2], acc[i][j2], 0, 0, 0);
                    acc[i][j2] = __builtin_amdgcn_mfma_f32_16x16x32_bf16(
                        qfl_[i][kk], fbh[j2], acc[i][j2], 0, 0, 0);
                }
        }
        __builtin_amdgcn_s_setprio(0);

#pragma unroll
        for (int i = 0; i < 2; ++i)
#pragma unroll
            for (int r = 0; r < 4; ++r) {
                const int row = wrp * 32 + i * 16 + fq * 4 + r;
                const float cv = CEN[row], cc = C0S[row];
                float al = 0.f;
#pragma unroll
                for (int j2 = 0; j2 < 2; ++j2) {
                    const int col = wc * 32 + j2 * 16 + fr;
                    const float dd = (float)(j0 + col) - cv;
                    const float s  = acc[i][j2][r] * 0.125f - cc * dd * dd;
                    al += __expf(s - M0_SHIFT);
                }
                lsum[i][r] += al;
            }
    }

#pragma unroll
    for (int i = 0; i < 2; ++i)
#pragma unroll
        for (int r = 0; r < 4; ++r) {
            float v = lsum[i][r];
            v += __shfl_xor(v, 1);
            v += __shfl_xor(v, 2);
            v += __shfl_xor(v, 4);
            v += __shfl_xor(v, 8);
            if (fr == 0) LSUM[wc][wrp * 32 + i * 16 + fq * 4 + r] = v;
        }
    __syncthreads();
    if (t < 128) RINV[t] = 1.f / (LSUM[0][t] + LSUM[1][t]);

    // ---------------- PASS B ----------------
    f32v4 acco[2][2];
#pragma unroll
    for (int i = 0; i < 2; ++i)
#pragma unroll
        for (int j = 0; j < 2; ++j) acco[i][j] = zero;

    float* attnZ = attn + (size_t)z * 1024 * 1024;

    LOADK(0);
    LOADV(0);
    for (int jt = 0; jt < 16; ++jt) {
        const int j0 = jt * 64;
        __syncthreads();
        *(u16v8*)&KH[srow][ssl] = rkh;
        *(u16v8*)&KL[srow][ssl] = rkl;
        *(u16v8*)&VH[srow][ssl] = rvh;
        *(u16v8*)&VL[srow][ssl] = rvl;
        __syncthreads();
        if (jt < 15) { LOADK(j0 + 64); LOADV(j0 + 64); }

        f32v4 acc[2][2];
#pragma unroll
        for (int i = 0; i < 2; ++i)
#pragma unroll
            for (int j2 = 0; j2 < 2; ++j2) acc[i][j2] = zero;

        __builtin_amdgcn_s_setprio(1);
#pragma unroll
        for (int kk = 0; kk < 2; ++kk) {
            bf16v8 fbh[2], fbl[2];
#pragma unroll
            for (int j2 = 0; j2 < 2; ++j2) {
                const int rb = wc * 32 + j2 * 16 + fr;
                const int sb = ((kk * 4 + fq) ^ (rb & 7)) * 8;
                fbh[j2] = *(const bf16v8*)&KH[rb][sb];
                fbl[j2] = *(const bf16v8*)&KL[rb][sb];
            }
#pragma unroll
            for (int i = 0; i < 2; ++i)
#pragma unroll
                for (int j2 = 0; j2 < 2; ++j2) {
                    acc[i][j2] = __builtin_amdgcn_mfma_f32_16x16x32_bf16(
                        qfh_[i][kk], fbh[j2], acc[i][j2], 0, 0, 0);
                    acc[i][j2] = __builtin_amdgcn_mfma_f32_16x16x32_bf16(
                        qfh_[i][kk], fbl[j2], acc[i][j2], 0, 0, 0);
                    acc[i][j2] = __builtin_amdgcn_mfma_f32_16x16x32_bf16(
                        qfl_[i][kk], fbh[j2], acc[i][j2], 0, 0, 0);
                }
        }
        __builtin_amdgcn_s_setprio(0);

#pragma unroll
        for (int i = 0; i < 2; ++i)
#pragma unroll
            for (int r = 0; r < 4; ++r) {
                const int row = wrp * 32 + i * 16 + fq * 4 + r;
                const float cv = CEN[row], cc = C0S[row], ri = RINV[row];
#pragma unroll
                for (int j2 = 0; j2 < 2; ++j2) {
                    const int col = wc * 32 + j2 * 16 + fr;
                    const float dd = (float)(j0 + col) - cv;
                    const float s  = acc[i][j2][r] * 0.125f - cc * dd * dd;
                    const float p  = __expf(s - M0_SHIFT) * ri;
                    attnZ[(size_t)(i0 + row) * 1024 + j0 + col] = p;
                    unsigned short hv, lv;
                    split2(p, hv, lv);
                    const int slot = ((col >> 3) ^ (row & 7)) * 8 + (col & 7);
                    PH[row][slot] = hv;
                    PL[row][slot] = lv;
                }
            }
        __syncthreads();

        __builtin_amdgcn_s_setprio(1);
#pragma unroll
        for (int kk = 0; kk < 2; ++kk) {
            bf16v8 pah[2], pal[2], fbh[2], fbl[2];
#pragma unroll
            for (int iq = 0; iq < 2; ++iq) {
                const int rp = wrp * 32 + iq * 16 + fr;
                const int sp = ((kk * 4 + fq) ^ (rp & 7)) * 8;
                pah[iq] = *(const bf16v8*)&PH[rp][sp];
                pal[iq] = *(const bf16v8*)&PL[rp][sp];
            }
#pragma unroll
            for (int jd = 0; jd < 2; ++jd) {
                const int rb = wc * 32 + jd * 16 + fr;
                const int sb = ((kk * 4 + fq) ^ (rb & 7)) * 8;
                fbh[jd] = *(const bf16v8*)&VH[rb][sb];
                fbl[jd] = *(const bf16v8*)&VL[rb][sb];
            }
#pragma unroll
            for (int iq = 0; iq < 2; ++iq)
#pragma unroll
                for (int jd = 0; jd < 2; ++jd) {
                    acco[iq][jd] = __builtin_amdgcn_mfma_f32_16x16x32_bf16(
                        pah[iq], fbh[jd], acco[iq][jd], 0, 0, 0);
                    acco[iq][jd] = __builtin_amdgcn_mfma_f32_16x16x32_bf16(
                        pah[iq], fbl[jd], acco[iq][jd], 0, 0, 0);
                    acco[iq][jd] = __builtin_amdgcn_mfma_f32_16x16x32_bf16(
                        pal[iq], fbh[jd], acco[iq][jd], 0, 0, 0);
                }
        }
        __builtin_amdgcn_s_setprio(0);
    }

#pragma unroll
    for (int jd = 0; jd < 2; ++jd) {
        const int dcol = wc * 32 + jd * 16 + fr;
#pragma unroll
        for (int iq = 0; iq < 2; ++iq) {
            const int row0 = i0 + wrp * 32 + iq * 16 + fq * 4;
            const f32v4 cv = acco[iq][jd];
#pragma unroll
            for (int r = 0; r < 4; ++r) {
                unsigned short hv, lv;
                split2(cv[r], hv, lv);
                const size_t idx = (size_t)(bq * 1024 + row0 + r) * 1024 + hd * 64 + dcol;
                oh[idx] = hv;
                ol[idx] = lv;
            }
        }
    }
}

// ---------------------------------------------------------------------------
extern "C" void kernel_launch(void* const* d_in, const int* in_sizes, int n_in,
                              void* d_out, int out_size, void* d_ws, size_t ws_size,
                              hipStream_t stream)
{
    const float* query = (const float*)d_in[0];
    const float* key_  = (const float*)d_in[1];
    const float* value = (const float*)d_in[2];
    const float* Wq  = (const float*)d_in[3];
    const float* bq  = (const float*)d_in[4];
    const float* Wk  = (const float*)d_in[5];
    const float* bk  = (const float*)d_in[6];
    const float* Wv  = (const float*)d_in[7];
    const float* bv  = (const float*)d_in[8];
    const float* Wp  = (const float*)d_in[9];
    const float* bp  = (const float*)d_in[10];
    const float* Wup = (const float*)d_in[11];
    const float* bup = (const float*)d_in[12];
    const float* Wud = (const float*)d_in[13];
    const float* bud = (const float*)d_in[14];
    const float* Wus = (const float*)d_in[15];
    const float* bus = (const float*)d_in[16];
    const float* Wo  = (const float*)d_in[17];
    const float* bo  = (const float*)d_in[18];

    float* x_out = (float*)d_out;                         // [4096,1024]
    float* attn  = x_out + (size_t)MTOT * HIDN;           // [64,1024,1024]

    // ---- workspace layout (bytes)
    char* wsb = (char*)d_ws;
    unsigned short* qh  = (unsigned short*)(wsb);                  // 8 MB
    unsigned short* ql  = (unsigned short*)(wsb + (8u  << 20));
    unsigned short* kh  = (unsigned short*)(wsb + (16u << 20));
    unsigned short* kl  = (unsigned short*)(wsb + (24u << 20));
    unsigned short* vTh = (unsigned short*)(wsb + (32u << 20));
    unsigned short* vTl = (unsigned short*)(wsb + (40u << 20));
    unsigned short* oh  = (unsigned short*)(wsb + (48u << 20));    // 8 MB
    unsigned short* ol  = (unsigned short*)(wsb + (56u << 20));
    float* alpha_ws = (float*)(wsb + (64u << 20));                 // 256 KB
    float* cen_ws   = (float*)(wsb + (64u << 20) + (256u << 10));
    float* c0_ws    = (float*)(wsb + (64u << 20) + (512u << 10));
    float* bqp_ws   = (float*)(wsb + (64u << 20) + (768u << 10));  // 4 KB
    // weight splits live in the (not-yet-written) attn region
    unsigned short* wh  = (unsigned short*)attn;                   // slots 0..3 (8 MB)
    unsigned short* wl  = wh + (size_t)4 * 1024 * 1024;            // 8 MB
    unsigned short* w5h = wl + (size_t)4 * 1024 * 1024;            // Wqp hi (2 MB)
    unsigned short* w5l = w5h + (size_t)1024 * 1024;               // Wqp lo (2 MB)
    // Wo split reuses qh/ql space after attn_fused
    unsigned short* w2h = qh;
    unsigned short* w2l = ql;

    const dim3 blk(256);
    const dim3 blk512(512);
    const size_t WSTEP = (size_t)1024 * 1024;
    (void)WSTEP;

    // independent prep: bqp, weight splits, alpha
    bqp_kernel<<<dim3(16), blk, 0, stream>>>(bq, Wp, bp, bqp_ws);
    split_w4<<<dim3(16, 16, 4), blk, 0, stream>>>(Wq, Wk, Wv, Wp, wh, wl);
    alpha_kernel<<<dim3(MTOT / 16), blk, 0, stream>>>(query, Wus, bus, alpha_ws);
    // Wqp = Wq @ Wp  (bf16x3, output transposed hi/lo split)
    gemm_t<1, 4><<<dim3(16, 8), blk512, 0, stream>>>(
        Wq, nullptr, nullptr, wh + 3 * WSTEP, wl + 3 * WSTEP,
        nullptr, nullptr, w5h, w5l);
    // batched projections: q, k, v, cen/c0 — one dispatch, 2048 blocks
    gemm_batched<<<dim3(16, 32, 4), blk512, 0, stream>>>(
        query, key_, value, wh, wl, w5h, w5l,
        bq, bk, bv, bqp_ws,
        qh, ql, kh, kl, vTh, vTl,
        Wup, Wud, bup, bud, alpha_ws, cen_ws, c0_ws);
    // fused scores + softmax + attn-write + PV
    attn_fused<<<dim3(512), blk512, 0, stream>>>(
        qh, ql, kh, kl, vTh, vTl, cen_ws, c0_ws, attn, oh, ol);
    // Wo split (into dead qh/ql region), then x = o @ Wo + bo
    split_w4<<<dim3(16, 16, 1), blk, 0, stream>>>(Wo, Wo, Wo, Wo, w2h, w2l);
    gemm_t<0, 0><<<dim3(16, 32), blk512, 0, stream>>>(
        nullptr, oh, ol, w2h, w2l, bo, x_out, nullptr, nullptr);
}

// Round 11
// 380.717 us; speedup vs baseline: 1.0370x; 1.0370x over previous
//
#include <hip/hip_runtime.h>
#include <hip/hip_bf16.h>
#include <math.h>

#define S_LEN 1024
#define HIDN  1024
#define NHEAD 16
#define HDIM  64
#define BATCH 4
#define MTOT  (BATCH * S_LEN)   // 4096

typedef __attribute__((ext_vector_type(8))) short          bf16v8;
typedef __attribute__((ext_vector_type(8))) unsigned short u16v8;
typedef __attribute__((ext_vector_type(4))) unsigned short u16v4;
typedef __attribute__((ext_vector_type(4))) float          f32v4;

// ---------------------------------------------------------------------------
// bf16 hi/lo split helpers (RNE)
// ---------------------------------------------------------------------------
__device__ __forceinline__ unsigned short f2bf_rne(float x) {
    unsigned int u = __float_as_uint(x);
    unsigned int r = (u + 0x7fffu + ((u >> 16) & 1u)) >> 16;
    return (unsigned short)r;
}
__device__ __forceinline__ float bf2f(unsigned short h) {
    return __uint_as_float(((unsigned int)h) << 16);
}
__device__ __forceinline__ void split2(float x, unsigned short& h, unsigned short& l) {
    h = f2bf_rne(x);
    l = f2bf_rne(x - bf2f(h));
}

// ---------------------------------------------------------------------------
// split_w4: z-batched weight split. W f32 [K][N] -> transposed hi/lo [N][K].
// ---------------------------------------------------------------------------
__global__ __launch_bounds__(256) void split_w4(
    const float* __restrict__ W0, const float* __restrict__ W1,
    const float* __restrict__ W2, const float* __restrict__ W3,
    unsigned short* __restrict__ Hbase, unsigned short* __restrict__ Lbase)
{
    __shared__ float T[64][65];
    const int t  = threadIdx.x;
    const int k0 = blockIdx.y * 64;
    const int n0 = blockIdx.x * 64;
    const int z  = blockIdx.z;
    const float* W = (z == 0) ? W0 : (z == 1) ? W1 : (z == 2) ? W2 : W3;
    unsigned short* H = Hbase + (size_t)z * 1024 * 1024;
    unsigned short* L = Lbase + (size_t)z * 1024 * 1024;

    const int r = t >> 4;
    const int c = (t & 15) * 4;
#pragma unroll
    for (int i = 0; i < 4; ++i) {
        const int rr = r + i * 16;
        const float4 v = *(const float4*)&W[(size_t)(k0 + rr) * 1024 + n0 + c];
        T[rr][c + 0] = v.x; T[rr][c + 1] = v.y;
        T[rr][c + 2] = v.z; T[rr][c + 3] = v.w;
    }
    __syncthreads();

    const int n  = t >> 2;
    const int ko = (t & 3) * 16;
    u16v8 h0, h1, l0, l1;
#pragma unroll
    for (int kk = 0; kk < 8; ++kk) {
        unsigned short hh, ll;
        split2(T[ko + kk][n], hh, ll);
        h0[kk] = hh; l0[kk] = ll;
    }
#pragma unroll
    for (int kk = 0; kk < 8; ++kk) {
        unsigned short hh, ll;
        split2(T[ko + 8 + kk][n], hh, ll);
        h1[kk] = hh; l1[kk] = ll;
    }
    unsigned short* Hp = &H[(size_t)(n0 + n) * 1024 + k0 + ko];
    unsigned short* Lp = &L[(size_t)(n0 + n) * 1024 + k0 + ko];
    *(u16v8*)(Hp)     = h0;
    *(u16v8*)(Hp + 8) = h1;
    *(u16v8*)(Lp)     = l0;
    *(u16v8*)(Lp + 8) = l1;
}

// ---------------------------------------------------------------------------
// alpha = sigmoid(query @ Wus + bus)   [MTOT,16]
// ---------------------------------------------------------------------------
__global__ __launch_bounds__(256) void alpha_kernel(
    const float* __restrict__ X, const float* __restrict__ Wus,
    const float* __restrict__ bus, float* __restrict__ alpha)
{
    __shared__ float Ws[1024 * 16];
    const int t = threadIdx.x;
#pragma unroll
    for (int i = 0; i < 16; ++i) {
        const int idx = t + i * 256;
        *reinterpret_cast<float4*>(&Ws[idx * 4]) =
            *reinterpret_cast<const float4*>(&Wus[idx * 4]);
    }
    __syncthreads();

    const int r = t >> 4, c = t & 15;
    const size_t row = (size_t)blockIdx.x * 16 + r;
    const float* x = &X[row * 1024];
    float acc = 0.f;
    for (int kk = 0; kk < 1024; kk += 4) {
        const float4 xv = *reinterpret_cast<const float4*>(&x[kk]);
        acc = fmaf(xv.x, Ws[(kk + 0) * 16 + c], acc);
        acc = fmaf(xv.y, Ws[(kk + 1) * 16 + c], acc);
        acc = fmaf(xv.z, Ws[(kk + 2) * 16 + c], acc);
        acc = fmaf(xv.w, Ws[(kk + 3) * 16 + c], acc);
    }
    acc += bus[c];
    alpha[row * 16 + c] = 1.f / (1.f + expf(-acc));
}

// ---------------------------------------------------------------------------
// Templated bf16x3 MFMA GEMM. BM=128, BN=64, BK=32, 512 threads (8 waves 4x2),
// wave 32x32 out, launch_bounds(512,2) -> 128 VGPR cap, no spill.
// AF32: 1 = A is raw f32 (split inline during staging), 0 = pre-split bf16.
// EPI:  0 = f32 out (+bias), 1 = bf16 hi/lo out, 2 = per-head-transposed
//       bf16 out (for V), 3 = fused posparam (p never materialized).
// ---------------------------------------------------------------------------
template<int AF32, int EPI>
__global__ __launch_bounds__(512, 2) void gemm_t(
    const float* __restrict__ Af,
    const unsigned short* __restrict__ Ah, const unsigned short* __restrict__ Al,
    const unsigned short* __restrict__ Bh, const unsigned short* __restrict__ Bl,
    const float* __restrict__ bias, float* __restrict__ Cf,
    unsigned short* __restrict__ Ch, unsigned short* __restrict__ Cl,
    const float* __restrict__ Wup, const float* __restrict__ Wud,
    const float* __restrict__ bup, const float* __restrict__ bud,
    const float* __restrict__ alpha, float* __restrict__ cenp,
    float* __restrict__ c0p)
{
    __shared__ short Ash[128][40];
    __shared__ short Asl[128][40];
    __shared__ short Bsh[64][40];
    __shared__ short Bsl[64][40];
    __shared__ float PSUP[2][128], PSUD[2][128];

    const int t    = threadIdx.x;
    const int bm   = blockIdx.y * 128;
    const int bn   = blockIdx.x * 64;
    const int lane = t & 63;
    const int wid  = t >> 6;
    const int wr   = wid >> 1;
    const int wc   = wid & 1;
    const int fr   = lane & 15;
    const int fq   = lane >> 4;
    const int ks   = fq * 8;

    f32v4 zero = {0.f, 0.f, 0.f, 0.f};
    f32v4 acc[2][2];
#pragma unroll
    for (int i = 0; i < 2; ++i)
#pragma unroll
        for (int j = 0; j < 2; ++j) acc[i][j] = zero;

    const int sra = t >> 2;
    const int sca = (t & 3) * 8;
    const int tb  = t & 255;
    const int srb = tb >> 2;
    const int scb = (tb & 3) * 8;
    const bool isBl = (t >= 256);
    const unsigned short* pB = isBl ? &Bl[(size_t)(bn + srb) * 1024 + scb]
                                    : &Bh[(size_t)(bn + srb) * 1024 + scb];
    const float* pAf = AF32 ? &Af[(size_t)(bm + sra) * 1024 + sca] : nullptr;
    const unsigned short* pAh = AF32 ? nullptr : &Ah[(size_t)(bm + sra) * 1024 + sca];
    const unsigned short* pAl = AF32 ? nullptr : &Al[(size_t)(bm + sra) * 1024 + sca];

    u16v8 rah, ral, rb;
    auto LOAD = [&](int k0) {
        if (AF32) {
            const float4 a0 = *(const float4*)(pAf + k0);
            const float4 a1 = *(const float4*)(pAf + k0 + 4);
            const float xs[8] = {a0.x, a0.y, a0.z, a0.w, a1.x, a1.y, a1.z, a1.w};
#pragma unroll
            for (int e = 0; e < 8; ++e) {
                unsigned short hh, ll;
                split2(xs[e], hh, ll);
                rah[e] = hh; ral[e] = ll;
            }
        } else {
            rah = *(const u16v8*)(pAh + k0);
            ral = *(const u16v8*)(pAl + k0);
        }
        rb = *(const u16v8*)(pB + k0);
    };

    LOAD(0);
    for (int k0 = 0; k0 < 1024; k0 += 32) {
        __syncthreads();
        *(u16v8*)&Ash[sra][sca] = rah;
        *(u16v8*)&Asl[sra][sca] = ral;
        if (isBl) *(u16v8*)&Bsl[srb][scb] = rb;
        else      *(u16v8*)&Bsh[srb][scb] = rb;
        __syncthreads();

        if (k0 + 32 < 1024) LOAD(k0 + 32);

        bf16v8 fah[2], fal[2], fbh[2], fbl[2];
#pragma unroll
        for (int i = 0; i < 2; ++i) {
            fah[i] = *(const bf16v8*)&Ash[wr * 32 + i * 16 + fr][ks];
            fal[i] = *(const bf16v8*)&Asl[wr * 32 + i * 16 + fr][ks];
        }
#pragma unroll
        for (int j = 0; j < 2; ++j) {
            fbh[j] = *(const bf16v8*)&Bsh[wc * 32 + j * 16 + fr][ks];
            fbl[j] = *(const bf16v8*)&Bsl[wc * 32 + j * 16 + fr][ks];
        }
#pragma unroll
        for (int i = 0; i < 2; ++i)
#pragma unroll
            for (int j = 0; j < 2; ++j) {
                acc[i][j] = __builtin_amdgcn_mfma_f32_16x16x32_bf16(
                    fah[i], fbh[j], acc[i][j], 0, 0, 0);
                acc[i][j] = __builtin_amdgcn_mfma_f32_16x16x32_bf16(
                    fah[i], fbl[j], acc[i][j], 0, 0, 0);
                acc[i][j] = __builtin_amdgcn_mfma_f32_16x16x32_bf16(
                    fal[i], fbh[j], acc[i][j], 0, 0, 0);
            }
    }

    if (EPI == 3) {
        float wupj[2], wudj[2], bb[2];
#pragma unroll
        for (int j = 0; j < 2; ++j) {
            const int colL = wc * 32 + j * 16 + fr;
            wupj[j] = Wup[colL];
            wudj[j] = Wud[colL];
            bb[j]   = bias[bn + colL];
        }
        float su[2][4], sd[2][4];
#pragma unroll
        for (int i = 0; i < 2; ++i)
#pragma unroll
            for (int r = 0; r < 4; ++r) { su[i][r] = 0.f; sd[i][r] = 0.f; }
#pragma unroll
        for (int j = 0; j < 2; ++j)
#pragma unroll
            for (int i = 0; i < 2; ++i)
#pragma unroll
                for (int r = 0; r < 4; ++r) {
                    const float tv = tanhf(acc[i][j][r] + bb[j]);
                    su[i][r] = fmaf(tv, wupj[j], su[i][r]);
                    sd[i][r] = fmaf(tv, wudj[j], sd[i][r]);
                }
#pragma unroll
        for (int i = 0; i < 2; ++i)
#pragma unroll
            for (int r = 0; r < 4; ++r) {
                float a = su[i][r], d = sd[i][r];
                a += __shfl_xor(a, 1); d += __shfl_xor(d, 1);
                a += __shfl_xor(a, 2); d += __shfl_xor(d, 2);
                a += __shfl_xor(a, 4); d += __shfl_xor(d, 4);
                a += __shfl_xor(a, 8); d += __shfl_xor(d, 8);
                if (fr == 0) {
                    const int row = wr * 32 + i * 16 + fq * 4 + r;
                    PSUP[wc][row] = a;
                    PSUD[wc][row] = d;
                }
            }
        __syncthreads();
        if (t < 128) {
            const float ap = PSUP[0][t] + PSUP[1][t] + bup[0];
            const float az = PSUD[0][t] + PSUD[1][t] + bud[0];
            const float cenv = 1024.f / (1.f + expf(-ap));
            const float win  = 1024.f / (1.f + expf(-az));
            const int grow = bm + t;
            const int hd   = bn >> 6;
            const int zz   = (grow >> 10) * 16 + hd;
            const int s    = grow & 1023;
            const float al = alpha[(size_t)grow * 16 + hd];
            cenp[(size_t)zz * 1024 + s] = cenv;
            c0p[(size_t)zz * 1024 + s]  = al * 2.f / (win * win);
        }
        return;
    }

#pragma unroll
    for (int j = 0; j < 2; ++j) {
        const int col = bn + wc * 32 + j * 16 + fr;
        const float bb = bias[col];
#pragma unroll
        for (int i = 0; i < 2; ++i) {
            const int row0 = bm + wr * 32 + i * 16 + fq * 4;
            const f32v4 cv = acc[i][j];
            if (EPI == 2) {
                u16v4 h4, l4;
#pragma unroll
                for (int r = 0; r < 4; ++r) {
                    unsigned short hh, ll;
                    split2(cv[r] + bb, hh, ll);
                    h4[r] = hh; l4[r] = ll;
                }
                const size_t base =
                    ((size_t)((row0 >> 10) * 16 + (col >> 6)) * 64 + (col & 63)) * 1024
                    + (row0 & 1023);
                *(u16v4*)&Ch[base] = h4;
                *(u16v4*)&Cl[base] = l4;
            } else if (EPI == 1) {
#pragma unroll
                for (int r = 0; r < 4; ++r) {
                    unsigned short hh, ll;
                    split2(cv[r] + bb, hh, ll);
                    const size_t idx = (size_t)(row0 + r) * 1024 + col;
                    Ch[idx] = hh; Cl[idx] = ll;
                }
            } else {
#pragma unroll
                for (int r = 0; r < 4; ++r)
                    Cf[(size_t)(row0 + r) * 1024 + col] = cv[r] + bb;
            }
        }
    }
}

// ---------------------------------------------------------------------------
// attn_fused v6: pass-A K double-buffer (KH/KL <-> VH/VL, 1 barrier/tile) +
// s_setprio around MFMA clusters; otherwise the proven r8/r9 structure.
// ---------------------------------------------------------------------------
#define M0_SHIFT 8.0f
__global__ __launch_bounds__(512, 2) void attn_fused(
    const unsigned short* __restrict__ qh, const unsigned short* __restrict__ ql,
    const unsigned short* __restrict__ kh, const unsigned short* __restrict__ kl,
    const unsigned short* __restrict__ vTh, const unsigned short* __restrict__ vTl,
    const float* __restrict__ cen, const float* __restrict__ c0,
    float* __restrict__ attn,
    unsigned short* __restrict__ oh, unsigned short* __restrict__ ol)
{
    __shared__ unsigned short KH[64][64], KL[64][64];
    __shared__ unsigned short VH[64][64], VL[64][64];
    __shared__ unsigned short PH[128][64], PL[128][64];
    __shared__ float CEN[128], C0S[128];
    __shared__ float LSUM[2][128];
    __shared__ float RINV[128];

    const int bid   = blockIdx.x;
    const int z     = ((bid >> 6) << 3) | (bid & 7);
    const int itile = (bid >> 3) & 7;
    const int i0    = itile * 128;
    const int bq    = z >> 4;
    const int hd    = z & 15;

    const int t    = threadIdx.x;
    const int lane = t & 63;
    const int wid  = t >> 6;
    const int wrp  = wid >> 1;
    const int wc   = wid & 1;
    const int fr   = lane & 15, fq = lane >> 4;

    if (t < 128) {
        CEN[t] = cen[(size_t)z * 1024 + i0 + t];
        C0S[t] = c0[(size_t)z * 1024 + i0 + t];
    }

    bf16v8 qfh_[2][2], qfl_[2][2];
#pragma unroll
    for (int i = 0; i < 2; ++i)
#pragma unroll
        for (int kk = 0; kk < 2; ++kk) {
            const size_t qa = (size_t)(bq * 1024 + i0 + wrp * 32 + i * 16 + fr) * 1024
                              + hd * 64 + kk * 32 + fq * 8;
            qfh_[i][kk] = *(const bf16v8*)&qh[qa];
            qfl_[i][kk] = *(const bf16v8*)&ql[qa];
        }

    float lsum[2][4];
#pragma unroll
    for (int i = 0; i < 2; ++i)
#pragma unroll
        for (int r = 0; r < 4; ++r) lsum[i][r] = 0.f;

    const f32v4 zero = {0.f, 0.f, 0.f, 0.f};

    const int srow = t >> 3;
    const int sseg = t & 7;
    const int ssl  = (sseg ^ (srow & 7)) * 8;
    const unsigned short* vhb = vTh + (size_t)z * 64 * 1024;
    const unsigned short* vlb = vTl + (size_t)z * 64 * 1024;

    u16v8 rkh, rkl, rvh, rvl;
    auto LOADK = [&](int j0) {
        const size_t ga = (size_t)(bq * 1024 + j0 + srow) * 1024 + hd * 64 + sseg * 8;
        rkh = *(const u16v8*)&kh[ga];
        rkl = *(const u16v8*)&kl[ga];
    };
    auto LOADV = [&](int j0) {
        const size_t va = (size_t)srow * 1024 + j0 + sseg * 8;
        rvh = *(const u16v8*)&vhb[va];
        rvl = *(const u16v8*)&vlb[va];
    };

    // ---------------- PASS A: K double-buffered, 1 barrier/tile ----------
    LOADK(0);
    for (int jt = 0; jt < 16; ++jt) {
        const int j0 = jt * 64;
        unsigned short (*KHc)[64] = (jt & 1) ? VH : KH;
        unsigned short (*KLc)[64] = (jt & 1) ? VL : KL;
        *(u16v8*)&KHc[srow][ssl] = rkh;
        *(u16v8*)&KLc[srow][ssl] = rkl;
        __syncthreads();
        if (jt < 15) LOADK(j0 + 64);

        f32v4 acc[2][2];
#pragma unroll
        for (int i = 0; i < 2; ++i)
#pragma unroll
            for (int j2 = 0; j2 < 2; ++j2) acc[i][j2] = zero;

        __builtin_amdgcn_s_setprio(1);
#pragma unroll
        for (int kk = 0; kk < 2; ++kk) {
            bf16v8 fbh[2], fbl[2];
#pragma unroll
            for (int j2 = 0; j2 < 2; ++j2) {
                const int rb = wc * 32 + j2 * 16 + fr;
                const int sb = ((kk * 4 + fq) ^ (rb & 7)) * 8;
                fbh[j2] = *(const bf16v8*)&KHc[rb][sb];
                fbl[j2] = *(const bf16v8*)&KLc[rb][sb];
            }
#pragma unroll
            for (int i = 0; i < 2; ++i)
#pragma unroll
                for (int j2 = 0; j2 < 2; ++j2) {
                    acc[i][j2] = __builtin_amdgcn_mfma_f32_16x16x32_bf16(
                        qfh_[i][kk], fbh[j2], acc[i][j2], 0, 0, 0);
                    acc[i][j2] = __builtin_amdgcn_mfma_f32_16x16x32_bf16(
                        qfh_[i][kk], fbl[j2], acc[i][j2], 0, 0, 0);
                    acc[i][j2] = __builtin_amdgcn_mfma_f32_16x16x32_bf16(
                        qfl_[i][kk], fbh[j2], acc[i][j2], 0, 0, 0);
                }
        }
        __builtin_amdgcn_s_setprio(0);

#pragma unroll
        for (int i = 0; i < 2; ++i)
#pragma unroll
            for (int r = 0; r < 4; ++r) {
                const int row = wrp * 32 + i * 16 + fq * 4 + r;
                const float cv = CEN[row], cc = C0S[row];
                float al = 0.f;
#pragma unroll
                for (int j2 = 0; j2 < 2; ++j2) {
                    const int col = wc * 32 + j2 * 16 + fr;
                    const float dd = (float)(j0 + col) - cv;
                    const float s  = acc[i][j2][r] * 0.125f - cc * dd * dd;
                    al += __expf(s - M0_SHIFT);
                }
                lsum[i][r] += al;
            }
    }

#pragma unroll
    for (int i = 0; i < 2; ++i)
#pragma unroll
        for (int r = 0; r < 4; ++r) {
            float v = lsum[i][r];
            v += __shfl_xor(v, 1);
            v += __shfl_xor(v, 2);
            v += __shfl_xor(v, 4);
            v += __shfl_xor(v, 8);
            if (fr == 0) LSUM[wc][wrp * 32 + i * 16 + fq * 4 + r] = v;
        }
    __syncthreads();
    if (t < 128) RINV[t] = 1.f / (LSUM[0][t] + LSUM[1][t]);

    // ---------------- PASS B ----------------
    f32v4 acco[2][2];
#pragma unroll
    for (int i = 0; i < 2; ++i)
#pragma unroll
        for (int j = 0; j < 2; ++j) acco[i][j] = zero;

    float* attnZ = attn + (size_t)z * 1024 * 1024;

    LOADK(0);
    LOADV(0);
    for (int jt = 0; jt < 16; ++jt) {
        const int j0 = jt * 64;
        __syncthreads();
        *(u16v8*)&KH[srow][ssl] = rkh;
        *(u16v8*)&KL[srow][ssl] = rkl;
        *(u16v8*)&VH[srow][ssl] = rvh;
        *(u16v8*)&VL[srow][ssl] = rvl;
        __syncthreads();
        if (jt < 15) { LOADK(j0 + 64); LOADV(j0 + 64); }

        f32v4 acc[2][2];
#pragma unroll
        for (int i = 0; i < 2; ++i)
#pragma unroll
            for (int j2 = 0; j2 < 2; ++j2) acc[i][j2] = zero;

        __builtin_amdgcn_s_setprio(1);
#pragma unroll
        for (int kk = 0; kk < 2; ++kk) {
            bf16v8 fbh[2], fbl[2];
#pragma unroll
            for (int j2 = 0; j2 < 2; ++j2) {
                const int rb = wc * 32 + j2 * 16 + fr;
                const int sb = ((kk * 4 + fq) ^ (rb & 7)) * 8;
                fbh[j2] = *(const bf16v8*)&KH[rb][sb];
                fbl[j2] = *(const bf16v8*)&KL[rb][sb];
            }
#pragma unroll
            for (int i = 0; i < 2; ++i)
#pragma unroll
                for (int j2 = 0; j2 < 2; ++j2) {
                    acc[i][j2] = __builtin_amdgcn_mfma_f32_16x16x32_bf16(
                        qfh_[i][kk], fbh[j2], acc[i][j2], 0, 0, 0);
                    acc[i][j2] = __builtin_amdgcn_mfma_f32_16x16x32_bf16(
                        qfh_[i][kk], fbl[j2], acc[i][j2], 0, 0, 0);
                    acc[i][j2] = __builtin_amdgcn_mfma_f32_16x16x32_bf16(
                        qfl_[i][kk], fbh[j2], acc[i][j2], 0, 0, 0);
                }
        }
        __builtin_amdgcn_s_setprio(0);

#pragma unroll
        for (int i = 0; i < 2; ++i)
#pragma unroll
            for (int r = 0; r < 4; ++r) {
                const int row = wrp * 32 + i * 16 + fq * 4 + r;
                const float cv = CEN[row], cc = C0S[row], ri = RINV[row];
#pragma unroll
                for (int j2 = 0; j2 < 2; ++j2) {
                    const int col = wc * 32 + j2 * 16 + fr;
                    const float dd = (float)(j0 + col) - cv;
                    const float s  = acc[i][j2][r] * 0.125f - cc * dd * dd;
                    const float p  = __expf(s - M0_SHIFT) * ri;
                    attnZ[(size_t)(i0 + row) * 1024 + j0 + col] = p;
                    unsigned short hv, lv;
                    split2(p, hv, lv);
                    const int slot = ((col >> 3) ^ (row & 7)) * 8 + (col & 7);
                    PH[row][slot] = hv;
                    PL[row][slot] = lv;
                }
            }
        __syncthreads();

        __builtin_amdgcn_s_setprio(1);
#pragma unroll
        for (int kk = 0; kk < 2; ++kk) {
            bf16v8 pah[2], pal[2], fbh[2], fbl[2];
#pragma unroll
            for (int iq = 0; iq < 2; ++iq) {
                const int rp = wrp * 32 + iq * 16 + fr;
                const int sp = ((kk * 4 + fq) ^ (rp & 7)) * 8;
                pah[iq] = *(const bf16v8*)&PH[rp][sp];
                pal[iq] = *(const bf16v8*)&PL[rp][sp];
            }
#pragma unroll
            for (int jd = 0; jd < 2; ++jd) {
                const int rb = wc * 32 + jd * 16 + fr;
                const int sb = ((kk * 4 + fq) ^ (rb & 7)) * 8;
                fbh[jd] = *(const bf16v8*)&VH[rb][sb];
                fbl[jd] = *(const bf16v8*)&VL[rb][sb];
            }
#pragma unroll
            for (int iq = 0; iq < 2; ++iq)
#pragma unroll
                for (int jd = 0; jd < 2; ++jd) {
                    acco[iq][jd] = __builtin_amdgcn_mfma_f32_16x16x32_bf16(
                        pah[iq], fbh[jd], acco[iq][jd], 0, 0, 0);
                    acco[iq][jd] = __builtin_amdgcn_mfma_f32_16x16x32_bf16(
                        pah[iq], fbl[jd], acco[iq][jd], 0, 0, 0);
                    acco[iq][jd] = __builtin_amdgcn_mfma_f32_16x16x32_bf16(
                        pal[iq], fbh[jd], acco[iq][jd], 0, 0, 0);
                }
        }
        __builtin_amdgcn_s_setprio(0);
    }

#pragma unroll
    for (int jd = 0; jd < 2; ++jd) {
        const int dcol = wc * 32 + jd * 16 + fr;
#pragma unroll
        for (int iq = 0; iq < 2; ++iq) {
            const int row0 = i0 + wrp * 32 + iq * 16 + fq * 4;
            const f32v4 cv = acco[iq][jd];
#pragma unroll
            for (int r = 0; r < 4; ++r) {
                unsigned short hv, lv;
                split2(cv[r], hv, lv);
                const size_t idx = (size_t)(bq * 1024 + row0 + r) * 1024 + hd * 64 + dcol;
                oh[idx] = hv;
                ol[idx] = lv;
            }
        }
    }
}

// ---------------------------------------------------------------------------
extern "C" void kernel_launch(void* const* d_in, const int* in_sizes, int n_in,
                              void* d_out, int out_size, void* d_ws, size_t ws_size,
                              hipStream_t stream)
{
    const float* query = (const float*)d_in[0];
    const float* key_  = (const float*)d_in[1];
    const float* value = (const float*)d_in[2];
    const float* Wq  = (const float*)d_in[3];
    const float* bq  = (const float*)d_in[4];
    const float* Wk  = (const float*)d_in[5];
    const float* bk  = (const float*)d_in[6];
    const float* Wv  = (const float*)d_in[7];
    const float* bv  = (const float*)d_in[8];
    const float* Wp  = (const float*)d_in[9];
    const float* bp  = (const float*)d_in[10];
    const float* Wup = (const float*)d_in[11];
    const float* bup = (const float*)d_in[12];
    const float* Wud = (const float*)d_in[13];
    const float* bud = (const float*)d_in[14];
    const float* Wus = (const float*)d_in[15];
    const float* bus = (const float*)d_in[16];
    const float* Wo  = (const float*)d_in[17];
    const float* bo  = (const float*)d_in[18];

    float* x_out = (float*)d_out;                         // [4096,1024]
    float* attn  = x_out + (size_t)MTOT * HIDN;           // [64,1024,1024]

    // ---- workspace layout (bytes)
    char* wsb = (char*)d_ws;
    unsigned short* qh  = (unsigned short*)(wsb);                  // 8 MB
    unsigned short* ql  = (unsigned short*)(wsb + (8u  << 20));
    unsigned short* kh  = (unsigned short*)(wsb + (16u << 20));
    unsigned short* kl  = (unsigned short*)(wsb + (24u << 20));
    unsigned short* vTh = (unsigned short*)(wsb + (32u << 20));
    unsigned short* vTl = (unsigned short*)(wsb + (40u << 20));
    unsigned short* oh  = (unsigned short*)(wsb + (48u << 20));    // 8 MB
    unsigned short* ol  = (unsigned short*)(wsb + (56u << 20));
    float* alpha_ws = (float*)(wsb + (64u << 20));                 // 256 KB
    float* cen_ws   = (float*)(wsb + (64u << 20) + (256u << 10));
    float* c0_ws    = (float*)(wsb + (64u << 20) + (512u << 10));
    // weight splits for Wq/Wk/Wv/Wp live in the (not-yet-written) attn region
    unsigned short* wh = (unsigned short*)attn;                    // 4 x 2 MB
    unsigned short* wl = wh + (size_t)4 * 1024 * 1024;             // 4 x 2 MB
    // Wo split reuses qh/ql space after attn_fused
    unsigned short* w2h = qh;
    unsigned short* w2l = ql;

    const dim3 blk(256);
    const dim3 blk512(512);
    const dim3 ggemm(HIDN / 64, MTOT / 128);   // (16, 32) = 512 blocks
    const size_t WSTEP = (size_t)1024 * 1024;

    // weight splits (Wq,Wk,Wv,Wp) batched + alpha
    split_w4<<<dim3(16, 16, 4), blk, 0, stream>>>(Wq, Wk, Wv, Wp, wh, wl);
    alpha_kernel<<<dim3(MTOT / 16), blk, 0, stream>>>(query, Wus, bus, alpha_ws);
    // q = query @ Wq + bq -> qh/ql (inline f32-A split)
    gemm_t<1, 1><<<ggemm, blk512, 0, stream>>>(
        query, nullptr, nullptr, wh, wl, bq, nullptr, qh, ql,
        nullptr, nullptr, nullptr, nullptr, nullptr, nullptr, nullptr);
    // k -> kh/kl
    gemm_t<1, 1><<<ggemm, blk512, 0, stream>>>(
        key_, nullptr, nullptr, wh + WSTEP, wl + WSTEP, bk, nullptr, kh, kl,
        nullptr, nullptr, nullptr, nullptr, nullptr, nullptr, nullptr);
    // v -> vTh/vTl (per-head transposed)
    gemm_t<1, 2><<<ggemm, blk512, 0, stream>>>(
        value, nullptr, nullptr, wh + 2 * WSTEP, wl + 2 * WSTEP, bv,
        nullptr, vTh, vTl,
        nullptr, nullptr, nullptr, nullptr, nullptr, nullptr, nullptr);
    // p = q @ Wp + bp with fused posparam -> cen/c0 (p never materialized)
    gemm_t<0, 3><<<ggemm, blk512, 0, stream>>>(
        nullptr, qh, ql, wh + 3 * WSTEP, wl + 3 * WSTEP, bp, nullptr,
        nullptr, nullptr,
        Wup, Wud, bup, bud, alpha_ws, cen_ws, c0_ws);
    // fused scores + softmax + attn-write + PV
    attn_fused<<<dim3(512), blk512, 0, stream>>>(
        qh, ql, kh, kl, vTh, vTl, cen_ws, c0_ws, attn, oh, ol);
    // Wo split (into dead qh/ql region), then x = o @ Wo + bo
    split_w4<<<dim3(16, 16, 1), blk, 0, stream>>>(Wo, Wo, Wo, Wo, w2h, w2l);
    gemm_t<0, 0><<<ggemm, blk512, 0, stream>>>(
        nullptr, oh, ol, w2h, w2l, bo, x_out, nullptr, nullptr,
        nullptr, nullptr, nullptr, nullptr, nullptr, nullptr, nullptr);
}

// Round 12
// 368.076 us; speedup vs baseline: 1.0726x; 1.0343x over previous
//
#include <hip/hip_runtime.h>
#include <hip/hip_bf16.h>
#include <math.h>

#define S_LEN 1024
#define HIDN  1024
#define NHEAD 16
#define HDIM  64
#define BATCH 4
#define MTOT  (BATCH * S_LEN)   // 4096

typedef __attribute__((ext_vector_type(8))) short          bf16v8;
typedef __attribute__((ext_vector_type(8))) unsigned short u16v8;
typedef __attribute__((ext_vector_type(4))) unsigned short u16v4;
typedef __attribute__((ext_vector_type(4))) float          f32v4;

// ---------------------------------------------------------------------------
// bf16 hi/lo split helpers (RNE)
// ---------------------------------------------------------------------------
__device__ __forceinline__ unsigned short f2bf_rne(float x) {
    unsigned int u = __float_as_uint(x);
    unsigned int r = (u + 0x7fffu + ((u >> 16) & 1u)) >> 16;
    return (unsigned short)r;
}
__device__ __forceinline__ float bf2f(unsigned short h) {
    return __uint_as_float(((unsigned int)h) << 16);
}
__device__ __forceinline__ void split2(float x, unsigned short& h, unsigned short& l) {
    h = f2bf_rne(x);
    l = f2bf_rne(x - bf2f(h));
}

// ---------------------------------------------------------------------------
// split_w4: z-batched weight split. W f32 [K][N] -> transposed hi/lo [N][K].
// ---------------------------------------------------------------------------
__global__ __launch_bounds__(256) void split_w4(
    const float* __restrict__ W0, const float* __restrict__ W1,
    const float* __restrict__ W2, const float* __restrict__ W3,
    unsigned short* __restrict__ Hbase, unsigned short* __restrict__ Lbase)
{
    __shared__ float T[64][65];
    const int t  = threadIdx.x;
    const int k0 = blockIdx.y * 64;
    const int n0 = blockIdx.x * 64;
    const int z  = blockIdx.z;
    const float* W = (z == 0) ? W0 : (z == 1) ? W1 : (z == 2) ? W2 : W3;
    unsigned short* H = Hbase + (size_t)z * 1024 * 1024;
    unsigned short* L = Lbase + (size_t)z * 1024 * 1024;

    const int r = t >> 4;
    const int c = (t & 15) * 4;
#pragma unroll
    for (int i = 0; i < 4; ++i) {
        const int rr = r + i * 16;
        const float4 v = *(const float4*)&W[(size_t)(k0 + rr) * 1024 + n0 + c];
        T[rr][c + 0] = v.x; T[rr][c + 1] = v.y;
        T[rr][c + 2] = v.z; T[rr][c + 3] = v.w;
    }
    __syncthreads();

    const int n  = t >> 2;
    const int ko = (t & 3) * 16;
    u16v8 h0, h1, l0, l1;
#pragma unroll
    for (int kk = 0; kk < 8; ++kk) {
        unsigned short hh, ll;
        split2(T[ko + kk][n], hh, ll);
        h0[kk] = hh; l0[kk] = ll;
    }
#pragma unroll
    for (int kk = 0; kk < 8; ++kk) {
        unsigned short hh, ll;
        split2(T[ko + 8 + kk][n], hh, ll);
        h1[kk] = hh; l1[kk] = ll;
    }
    unsigned short* Hp = &H[(size_t)(n0 + n) * 1024 + k0 + ko];
    unsigned short* Lp = &L[(size_t)(n0 + n) * 1024 + k0 + ko];
    *(u16v8*)(Hp)     = h0;
    *(u16v8*)(Hp + 8) = h1;
    *(u16v8*)(Lp)     = l0;
    *(u16v8*)(Lp + 8) = l1;
}

// ---------------------------------------------------------------------------
// alpha = sigmoid(query @ Wus + bus)   [MTOT,16]
// ---------------------------------------------------------------------------
__global__ __launch_bounds__(256) void alpha_kernel(
    const float* __restrict__ X, const float* __restrict__ Wus,
    const float* __restrict__ bus, float* __restrict__ alpha)
{
    __shared__ float Ws[1024 * 16];
    const int t = threadIdx.x;
#pragma unroll
    for (int i = 0; i < 16; ++i) {
        const int idx = t + i * 256;
        *reinterpret_cast<float4*>(&Ws[idx * 4]) =
            *reinterpret_cast<const float4*>(&Wus[idx * 4]);
    }
    __syncthreads();

    const int r = t >> 4, c = t & 15;
    const size_t row = (size_t)blockIdx.x * 16 + r;
    const float* x = &X[row * 1024];
    float acc = 0.f;
    for (int kk = 0; kk < 1024; kk += 4) {
        const float4 xv = *reinterpret_cast<const float4*>(&x[kk]);
        acc = fmaf(xv.x, Ws[(kk + 0) * 16 + c], acc);
        acc = fmaf(xv.y, Ws[(kk + 1) * 16 + c], acc);
        acc = fmaf(xv.z, Ws[(kk + 2) * 16 + c], acc);
        acc = fmaf(xv.w, Ws[(kk + 3) * 16 + c], acc);
    }
    acc += bus[c];
    alpha[row * 16 + c] = 1.f / (1.f + expf(-acc));
}

// ---------------------------------------------------------------------------
// Templated bf16x3 MFMA GEMM. BM=128, BN=64, BK=64 (16 iterations, half the
// barrier drains of BK=32), 512 threads (8 waves 4x2), wave 32x32 out,
// launch_bounds(512,2). LDS rows padded to 72 shorts (bank-even for b128).
// AF32: 1 = A is raw f32 (split inline during staging), 0 = pre-split bf16.
// EPI:  0 = f32 out (+bias), 1 = bf16 hi/lo out, 2 = per-head-transposed
//       bf16 out (for V), 3 = fused posparam (p never materialized).
// ---------------------------------------------------------------------------
template<int AF32, int EPI>
__global__ __launch_bounds__(512, 2) void gemm_t(
    const float* __restrict__ Af,
    const unsigned short* __restrict__ Ah, const unsigned short* __restrict__ Al,
    const unsigned short* __restrict__ Bh, const unsigned short* __restrict__ Bl,
    const float* __restrict__ bias, float* __restrict__ Cf,
    unsigned short* __restrict__ Ch, unsigned short* __restrict__ Cl,
    const float* __restrict__ Wup, const float* __restrict__ Wud,
    const float* __restrict__ bup, const float* __restrict__ bud,
    const float* __restrict__ alpha, float* __restrict__ cenp,
    float* __restrict__ c0p)
{
    __shared__ short Ash[128][72];
    __shared__ short Asl[128][72];
    __shared__ short Bsh[64][72];
    __shared__ short Bsl[64][72];
    __shared__ float PSUP[2][128], PSUD[2][128];

    const int t    = threadIdx.x;
    const int bm   = blockIdx.y * 128;
    const int bn   = blockIdx.x * 64;
    const int lane = t & 63;
    const int wid  = t >> 6;
    const int wr   = wid >> 1;
    const int wc   = wid & 1;
    const int fr   = lane & 15;
    const int fq   = lane >> 4;

    f32v4 zero = {0.f, 0.f, 0.f, 0.f};
    f32v4 acc[2][2];
#pragma unroll
    for (int i = 0; i < 2; ++i)
#pragma unroll
        for (int j = 0; j < 2; ++j) acc[i][j] = zero;

    // staging roles (BK=64): A: thread -> row t>>2 (0..127), 16-short chunk
    // (t&3)*16. B: 256-thread halves (h/l): row tb>>2 (0..63), chunk (tb&3)*16.
    const int sra = t >> 2;
    const int sca = (t & 3) * 16;
    const int tb  = t & 255;
    const int srb = tb >> 2;
    const int scb = (tb & 3) * 16;
    const bool isBl = (t >= 256);
    const unsigned short* pB = isBl ? &Bl[(size_t)(bn + srb) * 1024 + scb]
                                    : &Bh[(size_t)(bn + srb) * 1024 + scb];
    const float* pAf = AF32 ? &Af[(size_t)(bm + sra) * 1024 + sca] : nullptr;
    const unsigned short* pAh = AF32 ? nullptr : &Ah[(size_t)(bm + sra) * 1024 + sca];
    const unsigned short* pAl = AF32 ? nullptr : &Al[(size_t)(bm + sra) * 1024 + sca];

    u16v8 rah0, rah1, ral0, ral1, rb0, rb1;
    auto LOAD = [&](int k0) {
        if (AF32) {
            const float4 a0 = *(const float4*)(pAf + k0);
            const float4 a1 = *(const float4*)(pAf + k0 + 4);
            const float4 a2 = *(const float4*)(pAf + k0 + 8);
            const float4 a3 = *(const float4*)(pAf + k0 + 12);
            const float xs[16] = {a0.x, a0.y, a0.z, a0.w, a1.x, a1.y, a1.z, a1.w,
                                  a2.x, a2.y, a2.z, a2.w, a3.x, a3.y, a3.z, a3.w};
#pragma unroll
            for (int e = 0; e < 8; ++e) {
                unsigned short hh, ll;
                split2(xs[e], hh, ll);
                rah0[e] = hh; ral0[e] = ll;
            }
#pragma unroll
            for (int e = 0; e < 8; ++e) {
                unsigned short hh, ll;
                split2(xs[8 + e], hh, ll);
                rah1[e] = hh; ral1[e] = ll;
            }
        } else {
            rah0 = *(const u16v8*)(pAh + k0);
            rah1 = *(const u16v8*)(pAh + k0 + 8);
            ral0 = *(const u16v8*)(pAl + k0);
            ral1 = *(const u16v8*)(pAl + k0 + 8);
        }
        rb0 = *(const u16v8*)(pB + k0);
        rb1 = *(const u16v8*)(pB + k0 + 8);
    };

    LOAD(0);
    for (int k0 = 0; k0 < 1024; k0 += 64) {
        __syncthreads();
        *(u16v8*)&Ash[sra][sca]     = rah0;
        *(u16v8*)&Ash[sra][sca + 8] = rah1;
        *(u16v8*)&Asl[sra][sca]     = ral0;
        *(u16v8*)&Asl[sra][sca + 8] = ral1;
        if (isBl) {
            *(u16v8*)&Bsl[srb][scb]     = rb0;
            *(u16v8*)&Bsl[srb][scb + 8] = rb1;
        } else {
            *(u16v8*)&Bsh[srb][scb]     = rb0;
            *(u16v8*)&Bsh[srb][scb + 8] = rb1;
        }
        __syncthreads();

        if (k0 + 64 < 1024) LOAD(k0 + 64);

#pragma unroll
        for (int kk2 = 0; kk2 < 2; ++kk2) {
            const int ks = kk2 * 32 + fq * 8;
            bf16v8 fah[2], fal[2], fbh[2], fbl[2];
#pragma unroll
            for (int i = 0; i < 2; ++i) {
                fah[i] = *(const bf16v8*)&Ash[wr * 32 + i * 16 + fr][ks];
                fal[i] = *(const bf16v8*)&Asl[wr * 32 + i * 16 + fr][ks];
            }
#pragma unroll
            for (int j = 0; j < 2; ++j) {
                fbh[j] = *(const bf16v8*)&Bsh[wc * 32 + j * 16 + fr][ks];
                fbl[j] = *(const bf16v8*)&Bsl[wc * 32 + j * 16 + fr][ks];
            }
#pragma unroll
            for (int i = 0; i < 2; ++i)
#pragma unroll
                for (int j = 0; j < 2; ++j) {
                    acc[i][j] = __builtin_amdgcn_mfma_f32_16x16x32_bf16(
                        fah[i], fbh[j], acc[i][j], 0, 0, 0);
                    acc[i][j] = __builtin_amdgcn_mfma_f32_16x16x32_bf16(
                        fah[i], fbl[j], acc[i][j], 0, 0, 0);
                    acc[i][j] = __builtin_amdgcn_mfma_f32_16x16x32_bf16(
                        fal[i], fbh[j], acc[i][j], 0, 0, 0);
                }
        }
    }

    if (EPI == 3) {
        float wupj[2], wudj[2], bb[2];
#pragma unroll
        for (int j = 0; j < 2; ++j) {
            const int colL = wc * 32 + j * 16 + fr;
            wupj[j] = Wup[colL];
            wudj[j] = Wud[colL];
            bb[j]   = bias[bn + colL];
        }
        float su[2][4], sd[2][4];
#pragma unroll
        for (int i = 0; i < 2; ++i)
#pragma unroll
            for (int r = 0; r < 4; ++r) { su[i][r] = 0.f; sd[i][r] = 0.f; }
#pragma unroll
        for (int j = 0; j < 2; ++j)
#pragma unroll
            for (int i = 0; i < 2; ++i)
#pragma unroll
                for (int r = 0; r < 4; ++r) {
                    const float tv = tanhf(acc[i][j][r] + bb[j]);
                    su[i][r] = fmaf(tv, wupj[j], su[i][r]);
                    sd[i][r] = fmaf(tv, wudj[j], sd[i][r]);
                }
#pragma unroll
        for (int i = 0; i < 2; ++i)
#pragma unroll
            for (int r = 0; r < 4; ++r) {
                float a = su[i][r], d = sd[i][r];
                a += __shfl_xor(a, 1); d += __shfl_xor(d, 1);
                a += __shfl_xor(a, 2); d += __shfl_xor(d, 2);
                a += __shfl_xor(a, 4); d += __shfl_xor(d, 4);
                a += __shfl_xor(a, 8); d += __shfl_xor(d, 8);
                if (fr == 0) {
                    const int row = wr * 32 + i * 16 + fq * 4 + r;
                    PSUP[wc][row] = a;
                    PSUD[wc][row] = d;
                }
            }
        __syncthreads();
        if (t < 128) {
            const float ap = PSUP[0][t] + PSUP[1][t] + bup[0];
            const float az = PSUD[0][t] + PSUD[1][t] + bud[0];
            const float cenv = 1024.f / (1.f + expf(-ap));
            const float win  = 1024.f / (1.f + expf(-az));
            const int grow = bm + t;
            const int hd   = bn >> 6;
            const int zz   = (grow >> 10) * 16 + hd;
            const int s    = grow & 1023;
            const float al = alpha[(size_t)grow * 16 + hd];
            cenp[(size_t)zz * 1024 + s] = cenv;
            c0p[(size_t)zz * 1024 + s]  = al * 2.f / (win * win);
        }
        return;
    }

#pragma unroll
    for (int j = 0; j < 2; ++j) {
        const int col = bn + wc * 32 + j * 16 + fr;
        const float bb = bias[col];
#pragma unroll
        for (int i = 0; i < 2; ++i) {
            const int row0 = bm + wr * 32 + i * 16 + fq * 4;
            const f32v4 cv = acc[i][j];
            if (EPI == 2) {
                u16v4 h4, l4;
#pragma unroll
                for (int r = 0; r < 4; ++r) {
                    unsigned short hh, ll;
                    split2(cv[r] + bb, hh, ll);
                    h4[r] = hh; l4[r] = ll;
                }
                const size_t base =
                    ((size_t)((row0 >> 10) * 16 + (col >> 6)) * 64 + (col & 63)) * 1024
                    + (row0 & 1023);
                *(u16v4*)&Ch[base] = h4;
                *(u16v4*)&Cl[base] = l4;
            } else if (EPI == 1) {
#pragma unroll
                for (int r = 0; r < 4; ++r) {
                    unsigned short hh, ll;
                    split2(cv[r] + bb, hh, ll);
                    const size_t idx = (size_t)(row0 + r) * 1024 + col;
                    Ch[idx] = hh; Cl[idx] = ll;
                }
            } else {
#pragma unroll
                for (int r = 0; r < 4; ++r)
                    Cf[(size_t)(row0 + r) * 1024 + col] = cv[r] + bb;
            }
        }
    }
}

// ---------------------------------------------------------------------------
// attn_fused v6 (unchanged from round 11, 380-µs baseline): pass-A K
// double-buffer (KH/KL <-> VH/VL, 1 barrier/tile) + s_setprio around MFMA.
// ---------------------------------------------------------------------------
#define M0_SHIFT 8.0f
__global__ __launch_bounds__(512, 2) void attn_fused(
    const unsigned short* __restrict__ qh, const unsigned short* __restrict__ ql,
    const unsigned short* __restrict__ kh, const unsigned short* __restrict__ kl,
    const unsigned short* __restrict__ vTh, const unsigned short* __restrict__ vTl,
    const float* __restrict__ cen, const float* __restrict__ c0,
    float* __restrict__ attn,
    unsigned short* __restrict__ oh, unsigned short* __restrict__ ol)
{
    __shared__ unsigned short KH[64][64], KL[64][64];
    __shared__ unsigned short VH[64][64], VL[64][64];
    __shared__ unsigned short PH[128][64], PL[128][64];
    __shared__ float CEN[128], C0S[128];
    __shared__ float LSUM[2][128];
    __shared__ float RINV[128];

    const int bid   = blockIdx.x;
    const int z     = ((bid >> 6) << 3) | (bid & 7);
    const int itile = (bid >> 3) & 7;
    const int i0    = itile * 128;
    const int bq    = z >> 4;
    const int hd    = z & 15;

    const int t    = threadIdx.x;
    const int lane = t & 63;
    const int wid  = t >> 6;
    const int wrp  = wid >> 1;
    const int wc   = wid & 1;
    const int fr   = lane & 15, fq = lane >> 4;

    if (t < 128) {
        CEN[t] = cen[(size_t)z * 1024 + i0 + t];
        C0S[t] = c0[(size_t)z * 1024 + i0 + t];
    }

    bf16v8 qfh_[2][2], qfl_[2][2];
#pragma unroll
    for (int i = 0; i < 2; ++i)
#pragma unroll
        for (int kk = 0; kk < 2; ++kk) {
            const size_t qa = (size_t)(bq * 1024 + i0 + wrp * 32 + i * 16 + fr) * 1024
                              + hd * 64 + kk * 32 + fq * 8;
            qfh_[i][kk] = *(const bf16v8*)&qh[qa];
            qfl_[i][kk] = *(const bf16v8*)&ql[qa];
        }

    float lsum[2][4];
#pragma unroll
    for (int i = 0; i < 2; ++i)
#pragma unroll
        for (int r = 0; r < 4; ++r) lsum[i][r] = 0.f;

    const f32v4 zero = {0.f, 0.f, 0.f, 0.f};

    const int srow = t >> 3;
    const int sseg = t & 7;
    const int ssl  = (sseg ^ (srow & 7)) * 8;
    const unsigned short* vhb = vTh + (size_t)z * 64 * 1024;
    const unsigned short* vlb = vTl + (size_t)z * 64 * 1024;

    u16v8 rkh, rkl, rvh, rvl;
    auto LOADK = [&](int j0) {
        const size_t ga = (size_t)(bq * 1024 + j0 + srow) * 1024 + hd * 64 + sseg * 8;
        rkh = *(const u16v8*)&kh[ga];
        rkl = *(const u16v8*)&kl[ga];
    };
    auto LOADV = [&](int j0) {
        const size_t va = (size_t)srow * 1024 + j0 + sseg * 8;
        rvh = *(const u16v8*)&vhb[va];
        rvl = *(const u16v8*)&vlb[va];
    };

    // ---------------- PASS A: K double-buffered, 1 barrier/tile ----------
    LOADK(0);
    for (int jt = 0; jt < 16; ++jt) {
        const int j0 = jt * 64;
        unsigned short (*KHc)[64] = (jt & 1) ? VH : KH;
        unsigned short (*KLc)[64] = (jt & 1) ? VL : KL;
        *(u16v8*)&KHc[srow][ssl] = rkh;
        *(u16v8*)&KLc[srow][ssl] = rkl;
        __syncthreads();
        if (jt < 15) LOADK(j0 + 64);

        f32v4 acc[2][2];
#pragma unroll
        for (int i = 0; i < 2; ++i)
#pragma unroll
            for (int j2 = 0; j2 < 2; ++j2) acc[i][j2] = zero;

        __builtin_amdgcn_s_setprio(1);
#pragma unroll
        for (int kk = 0; kk < 2; ++kk) {
            bf16v8 fbh[2], fbl[2];
#pragma unroll
            for (int j2 = 0; j2 < 2; ++j2) {
                const int rb = wc * 32 + j2 * 16 + fr;
                const int sb = ((kk * 4 + fq) ^ (rb & 7)) * 8;
                fbh[j2] = *(const bf16v8*)&KHc[rb][sb];
                fbl[j2] = *(const bf16v8*)&KLc[rb][sb];
            }
#pragma unroll
            for (int i = 0; i < 2; ++i)
#pragma unroll
                for (int j2 = 0; j2 < 2; ++j2) {
                    acc[i][j2] = __builtin_amdgcn_mfma_f32_16x16x32_bf16(
                        qfh_[i][kk], fbh[j2], acc[i][j2], 0, 0, 0);
                    acc[i][j2] = __builtin_amdgcn_mfma_f32_16x16x32_bf16(
                        qfh_[i][kk], fbl[j2], acc[i][j2], 0, 0, 0);
                    acc[i][j2] = __builtin_amdgcn_mfma_f32_16x16x32_bf16(
                        qfl_[i][kk], fbh[j2], acc[i][j2], 0, 0, 0);
                }
        }
        __builtin_amdgcn_s_setprio(0);

#pragma unroll
        for (int i = 0; i < 2; ++i)
#pragma unroll
            for (int r = 0; r < 4; ++r) {
                const int row = wrp * 32 + i * 16 + fq * 4 + r;
                const float cv = CEN[row], cc = C0S[row];
                float al = 0.f;
#pragma unroll
                for (int j2 = 0; j2 < 2; ++j2) {
                    const int col = wc * 32 + j2 * 16 + fr;
                    const float dd = (float)(j0 + col) - cv;
                    const float s  = acc[i][j2][r] * 0.125f - cc * dd * dd;
                    al += __expf(s - M0_SHIFT);
                }
                lsum[i][r] += al;
            }
    }

#pragma unroll
    for (int i = 0; i < 2; ++i)
#pragma unroll
        for (int r = 0; r < 4; ++r) {
            float v = lsum[i][r];
            v += __shfl_xor(v, 1);
            v += __shfl_xor(v, 2);
            v += __shfl_xor(v, 4);
            v += __shfl_xor(v, 8);
            if (fr == 0) LSUM[wc][wrp * 32 + i * 16 + fq * 4 + r] = v;
        }
    __syncthreads();
    if (t < 128) RINV[t] = 1.f / (LSUM[0][t] + LSUM[1][t]);

    // ---------------- PASS B ----------------
    f32v4 acco[2][2];
#pragma unroll
    for (int i = 0; i < 2; ++i)
#pragma unroll
        for (int j = 0; j < 2; ++j) acco[i][j] = zero;

    float* attnZ = attn + (size_t)z * 1024 * 1024;

    LOADK(0);
    LOADV(0);
    for (int jt = 0; jt < 16; ++jt) {
        const int j0 = jt * 64;
        __syncthreads();
        *(u16v8*)&KH[srow][ssl] = rkh;
        *(u16v8*)&KL[srow][ssl] = rkl;
        *(u16v8*)&VH[srow][ssl] = rvh;
        *(u16v8*)&VL[srow][ssl] = rvl;
        __syncthreads();
        if (jt < 15) { LOADK(j0 + 64); LOADV(j0 + 64); }

        f32v4 acc[2][2];
#pragma unroll
        for (int i = 0; i < 2; ++i)
#pragma unroll
            for (int j2 = 0; j2 < 2; ++j2) acc[i][j2] = zero;

        __builtin_amdgcn_s_setprio(1);
#pragma unroll
        for (int kk = 0; kk < 2; ++kk) {
            bf16v8 fbh[2], fbl[2];
#pragma unroll
            for (int j2 = 0; j2 < 2; ++j2) {
                const int rb = wc * 32 + j2 * 16 + fr;
                const int sb = ((kk * 4 + fq) ^ (rb & 7)) * 8;
                fbh[j2] = *(const bf16v8*)&KH[rb][sb];
                fbl[j2] = *(const bf16v8*)&KL[rb][sb];
            }
#pragma unroll
            for (int i = 0; i < 2; ++i)
#pragma unroll
                for (int j2 = 0; j2 < 2; ++j2) {
                    acc[i][j2] = __builtin_amdgcn_mfma_f32_16x16x32_bf16(
                        qfh_[i][kk], fbh[j2], acc[i][j2], 0, 0, 0);
                    acc[i][j2] = __builtin_amdgcn_mfma_f32_16x16x32_bf16(
                        qfh_[i][kk], fbl[j2], acc[i][j2], 0, 0, 0);
                    acc[i][j2] = __builtin_amdgcn_mfma_f32_16x16x32_bf16(
                        qfl_[i][kk], fbh[j2], acc[i][j2], 0, 0, 0);
                }
        }
        __builtin_amdgcn_s_setprio(0);

#pragma unroll
        for (int i = 0; i < 2; ++i)
#pragma unroll
            for (int r = 0; r < 4; ++r) {
                const int row = wrp * 32 + i * 16 + fq * 4 + r;
                const float cv = CEN[row], cc = C0S[row], ri = RINV[row];
#pragma unroll
                for (int j2 = 0; j2 < 2; ++j2) {
                    const int col = wc * 32 + j2 * 16 + fr;
                    const float dd = (float)(j0 + col) - cv;
                    const float s  = acc[i][j2][r] * 0.125f - cc * dd * dd;
                    const float p  = __expf(s - M0_SHIFT) * ri;
                    attnZ[(size_t)(i0 + row) * 1024 + j0 + col] = p;
                    unsigned short hv, lv;
                    split2(p, hv, lv);
                    const int slot = ((col >> 3) ^ (row & 7)) * 8 + (col & 7);
                    PH[row][slot] = hv;
                    PL[row][slot] = lv;
                }
            }
        __syncthreads();

        __builtin_amdgcn_s_setprio(1);
#pragma unroll
        for (int kk = 0; kk < 2; ++kk) {
            bf16v8 pah[2], pal[2], fbh[2], fbl[2];
#pragma unroll
            for (int iq = 0; iq < 2; ++iq) {
                const int rp = wrp * 32 + iq * 16 + fr;
                const int sp = ((kk * 4 + fq) ^ (rp & 7)) * 8;
                pah[iq] = *(const bf16v8*)&PH[rp][sp];
                pal[iq] = *(const bf16v8*)&PL[rp][sp];
            }
#pragma unroll
            for (int jd = 0; jd < 2; ++jd) {
                const int rb = wc * 32 + jd * 16 + fr;
                const int sb = ((kk * 4 + fq) ^ (rb & 7)) * 8;
                fbh[jd] = *(const bf16v8*)&VH[rb][sb];
                fbl[jd] = *(const bf16v8*)&VL[rb][sb];
            }
#pragma unroll
            for (int iq = 0; iq < 2; ++iq)
#pragma unroll
                for (int jd = 0; jd < 2; ++jd) {
                    acco[iq][jd] = __builtin_amdgcn_mfma_f32_16x16x32_bf16(
                        pah[iq], fbh[jd], acco[iq][jd], 0, 0, 0);
                    acco[iq][jd] = __builtin_amdgcn_mfma_f32_16x16x32_bf16(
                        pah[iq], fbl[jd], acco[iq][jd], 0, 0, 0);
                    acco[iq][jd] = __builtin_amdgcn_mfma_f32_16x16x32_bf16(
                        pal[iq], fbh[jd], acco[iq][jd], 0, 0, 0);
                }
        }
        __builtin_amdgcn_s_setprio(0);
    }

#pragma unroll
    for (int jd = 0; jd < 2; ++jd) {
        const int dcol = wc * 32 + jd * 16 + fr;
#pragma unroll
        for (int iq = 0; iq < 2; ++iq) {
            const int row0 = i0 + wrp * 32 + iq * 16 + fq * 4;
            const f32v4 cv = acco[iq][jd];
#pragma unroll
            for (int r = 0; r < 4; ++r) {
                unsigned short hv, lv;
                split2(cv[r], hv, lv);
                const size_t idx = (size_t)(bq * 1024 + row0 + r) * 1024 + hd * 64 + dcol;
                oh[idx] = hv;
                ol[idx] = lv;
            }
        }
    }
}

// ---------------------------------------------------------------------------
extern "C" void kernel_launch(void* const* d_in, const int* in_sizes, int n_in,
                              void* d_out, int out_size, void* d_ws, size_t ws_size,
                              hipStream_t stream)
{
    const float* query = (const float*)d_in[0];
    const float* key_  = (const float*)d_in[1];
    const float* value = (const float*)d_in[2];
    const float* Wq  = (const float*)d_in[3];
    const float* bq  = (const float*)d_in[4];
    const float* Wk  = (const float*)d_in[5];
    const float* bk  = (const float*)d_in[6];
    const float* Wv  = (const float*)d_in[7];
    const float* bv  = (const float*)d_in[8];
    const float* Wp  = (const float*)d_in[9];
    const float* bp  = (const float*)d_in[10];
    const float* Wup = (const float*)d_in[11];
    const float* bup = (const float*)d_in[12];
    const float* Wud = (const float*)d_in[13];
    const float* bud = (const float*)d_in[14];
    const float* Wus = (const float*)d_in[15];
    const float* bus = (const float*)d_in[16];
    const float* Wo  = (const float*)d_in[17];
    const float* bo  = (const float*)d_in[18];

    float* x_out = (float*)d_out;                         // [4096,1024]
    float* attn  = x_out + (size_t)MTOT * HIDN;           // [64,1024,1024]

    // ---- workspace layout (bytes)
    char* wsb = (char*)d_ws;
    unsigned short* qh  = (unsigned short*)(wsb);                  // 8 MB
    unsigned short* ql  = (unsigned short*)(wsb + (8u  << 20));
    unsigned short* kh  = (unsigned short*)(wsb + (16u << 20));
    unsigned short* kl  = (unsigned short*)(wsb + (24u << 20));
    unsigned short* vTh = (unsigned short*)(wsb + (32u << 20));
    unsigned short* vTl = (unsigned short*)(wsb + (40u << 20));
    unsigned short* oh  = (unsigned short*)(wsb + (48u << 20));    // 8 MB
    unsigned short* ol  = (unsigned short*)(wsb + (56u << 20));
    float* alpha_ws = (float*)(wsb + (64u << 20));                 // 256 KB
    float* cen_ws   = (float*)(wsb + (64u << 20) + (256u << 10));
    float* c0_ws    = (float*)(wsb + (64u << 20) + (512u << 10));
    // weight splits for Wq/Wk/Wv/Wp live in the (not-yet-written) attn region
    unsigned short* wh = (unsigned short*)attn;                    // 4 x 2 MB
    unsigned short* wl = wh + (size_t)4 * 1024 * 1024;             // 4 x 2 MB
    // Wo split reuses qh/ql space after attn_fused
    unsigned short* w2h = qh;
    unsigned short* w2l = ql;

    const dim3 blk(256);
    const dim3 blk512(512);
    const dim3 ggemm(HIDN / 64, MTOT / 128);   // (16, 32) = 512 blocks
    const size_t WSTEP = (size_t)1024 * 1024;

    // weight splits (Wq,Wk,Wv,Wp) batched + alpha
    split_w4<<<dim3(16, 16, 4), blk, 0, stream>>>(Wq, Wk, Wv, Wp, wh, wl);
    alpha_kernel<<<dim3(MTOT / 16), blk, 0, stream>>>(query, Wus, bus, alpha_ws);
    // q = query @ Wq + bq -> qh/ql (inline f32-A split)
    gemm_t<1, 1><<<ggemm, blk512, 0, stream>>>(
        query, nullptr, nullptr, wh, wl, bq, nullptr, qh, ql,
        nullptr, nullptr, nullptr, nullptr, nullptr, nullptr, nullptr);
    // k -> kh/kl
    gemm_t<1, 1><<<ggemm, blk512, 0, stream>>>(
        key_, nullptr, nullptr, wh + WSTEP, wl + WSTEP, bk, nullptr, kh, kl,
        nullptr, nullptr, nullptr, nullptr, nullptr, nullptr, nullptr);
    // v -> vTh/vTl (per-head transposed)
    gemm_t<1, 2><<<ggemm, blk512, 0, stream>>>(
        value, nullptr, nullptr, wh + 2 * WSTEP, wl + 2 * WSTEP, bv,
        nullptr, vTh, vTl,
        nullptr, nullptr, nullptr, nullptr, nullptr, nullptr, nullptr);
    // p = q @ Wp + bp with fused posparam -> cen/c0 (p never materialized)
    gemm_t<0, 3><<<ggemm, blk512, 0, stream>>>(
        nullptr, qh, ql, wh + 3 * WSTEP, wl + 3 * WSTEP, bp, nullptr,
        nullptr, nullptr,
        Wup, Wud, bup, bud, alpha_ws, cen_ws, c0_ws);
    // fused scores + softmax + attn-write + PV
    attn_fused<<<dim3(512), blk512, 0, stream>>>(
        qh, ql, kh, kl, vTh, vTl, cen_ws, c0_ws, attn, oh, ol);
    // Wo split (into dead qh/ql region), then x = o @ Wo + bo
    split_w4<<<dim3(16, 16, 1), blk, 0, stream>>>(Wo, Wo, Wo, Wo, w2h, w2l);
    gemm_t<0, 0><<<ggemm, blk512, 0, stream>>>(
        nullptr, oh, ol, w2h, w2l, bo, x_out, nullptr, nullptr,
        nullptr, nullptr, nullptr, nullptr, nullptr, nullptr, nullptr);
}

// Round 13
// 365.717 us; speedup vs baseline: 1.0795x; 1.0065x over previous
//
#include <hip/hip_runtime.h>
#include <hip/hip_bf16.h>
#include <math.h>

#define S_LEN 1024
#define HIDN  1024
#define NHEAD 16
#define HDIM  64
#define BATCH 4
#define MTOT  (BATCH * S_LEN)   // 4096

typedef __attribute__((ext_vector_type(8))) short          bf16v8;
typedef __attribute__((ext_vector_type(8))) unsigned short u16v8;
typedef __attribute__((ext_vector_type(4))) unsigned short u16v4;
typedef __attribute__((ext_vector_type(4))) float          f32v4;

// ---------------------------------------------------------------------------
// bf16 hi/lo split helpers (RNE)
// ---------------------------------------------------------------------------
__device__ __forceinline__ unsigned short f2bf_rne(float x) {
    unsigned int u = __float_as_uint(x);
    unsigned int r = (u + 0x7fffu + ((u >> 16) & 1u)) >> 16;
    return (unsigned short)r;
}
__device__ __forceinline__ float bf2f(unsigned short h) {
    return __uint_as_float(((unsigned int)h) << 16);
}
__device__ __forceinline__ void split2(float x, unsigned short& h, unsigned short& l) {
    h = f2bf_rne(x);
    l = f2bf_rne(x - bf2f(h));
}

// ---------------------------------------------------------------------------
// split_w4: z-batched weight split. W f32 [K][N] -> transposed hi/lo [N][K].
// ---------------------------------------------------------------------------
__global__ __launch_bounds__(256) void split_w4(
    const float* __restrict__ W0, const float* __restrict__ W1,
    const float* __restrict__ W2, const float* __restrict__ W3,
    unsigned short* __restrict__ Hbase, unsigned short* __restrict__ Lbase)
{
    __shared__ float T[64][65];
    const int t  = threadIdx.x;
    const int k0 = blockIdx.y * 64;
    const int n0 = blockIdx.x * 64;
    const int z  = blockIdx.z;
    const float* W = (z == 0) ? W0 : (z == 1) ? W1 : (z == 2) ? W2 : W3;
    unsigned short* H = Hbase + (size_t)z * 1024 * 1024;
    unsigned short* L = Lbase + (size_t)z * 1024 * 1024;

    const int r = t >> 4;
    const int c = (t & 15) * 4;
#pragma unroll
    for (int i = 0; i < 4; ++i) {
        const int rr = r + i * 16;
        const float4 v = *(const float4*)&W[(size_t)(k0 + rr) * 1024 + n0 + c];
        T[rr][c + 0] = v.x; T[rr][c + 1] = v.y;
        T[rr][c + 2] = v.z; T[rr][c + 3] = v.w;
    }
    __syncthreads();

    const int n  = t >> 2;
    const int ko = (t & 3) * 16;
    u16v8 h0, h1, l0, l1;
#pragma unroll
    for (int kk = 0; kk < 8; ++kk) {
        unsigned short hh, ll;
        split2(T[ko + kk][n], hh, ll);
        h0[kk] = hh; l0[kk] = ll;
    }
#pragma unroll
    for (int kk = 0; kk < 8; ++kk) {
        unsigned short hh, ll;
        split2(T[ko + 8 + kk][n], hh, ll);
        h1[kk] = hh; l1[kk] = ll;
    }
    unsigned short* Hp = &H[(size_t)(n0 + n) * 1024 + k0 + ko];
    unsigned short* Lp = &L[(size_t)(n0 + n) * 1024 + k0 + ko];
    *(u16v8*)(Hp)     = h0;
    *(u16v8*)(Hp + 8) = h1;
    *(u16v8*)(Lp)     = l0;
    *(u16v8*)(Lp + 8) = l1;
}

// ---------------------------------------------------------------------------
// alpha = sigmoid(query @ Wus + bus)   [MTOT,16]
// ---------------------------------------------------------------------------
__global__ __launch_bounds__(256) void alpha_kernel(
    const float* __restrict__ X, const float* __restrict__ Wus,
    const float* __restrict__ bus, float* __restrict__ alpha)
{
    __shared__ float Ws[1024 * 16];
    const int t = threadIdx.x;
#pragma unroll
    for (int i = 0; i < 16; ++i) {
        const int idx = t + i * 256;
        *reinterpret_cast<float4*>(&Ws[idx * 4]) =
            *reinterpret_cast<const float4*>(&Wus[idx * 4]);
    }
    __syncthreads();

    const int r = t >> 4, c = t & 15;
    const size_t row = (size_t)blockIdx.x * 16 + r;
    const float* x = &X[row * 1024];
    float acc = 0.f;
    for (int kk = 0; kk < 1024; kk += 4) {
        const float4 xv = *reinterpret_cast<const float4*>(&x[kk]);
        acc = fmaf(xv.x, Ws[(kk + 0) * 16 + c], acc);
        acc = fmaf(xv.y, Ws[(kk + 1) * 16 + c], acc);
        acc = fmaf(xv.z, Ws[(kk + 2) * 16 + c], acc);
        acc = fmaf(xv.w, Ws[(kk + 3) * 16 + c], acc);
    }
    acc += bus[c];
    alpha[row * 16 + c] = 1.f / (1.f + expf(-acc));
}

// ---------------------------------------------------------------------------
// Templated bf16x3 MFMA GEMM. BM=128, BN=64, BK=64, 512 threads (8 waves),
// launch_bounds(512,2). (unchanged from round 12, proven)
// ---------------------------------------------------------------------------
template<int AF32, int EPI>
__global__ __launch_bounds__(512, 2) void gemm_t(
    const float* __restrict__ Af,
    const unsigned short* __restrict__ Ah, const unsigned short* __restrict__ Al,
    const unsigned short* __restrict__ Bh, const unsigned short* __restrict__ Bl,
    const float* __restrict__ bias, float* __restrict__ Cf,
    unsigned short* __restrict__ Ch, unsigned short* __restrict__ Cl,
    const float* __restrict__ Wup, const float* __restrict__ Wud,
    const float* __restrict__ bup, const float* __restrict__ bud,
    const float* __restrict__ alpha, float* __restrict__ cenp,
    float* __restrict__ c0p)
{
    __shared__ short Ash[128][72];
    __shared__ short Asl[128][72];
    __shared__ short Bsh[64][72];
    __shared__ short Bsl[64][72];
    __shared__ float PSUP[2][128], PSUD[2][128];

    const int t    = threadIdx.x;
    const int bm   = blockIdx.y * 128;
    const int bn   = blockIdx.x * 64;
    const int lane = t & 63;
    const int wid  = t >> 6;
    const int wr   = wid >> 1;
    const int wc   = wid & 1;
    const int fr   = lane & 15;
    const int fq   = lane >> 4;

    f32v4 zero = {0.f, 0.f, 0.f, 0.f};
    f32v4 acc[2][2];
#pragma unroll
    for (int i = 0; i < 2; ++i)
#pragma unroll
        for (int j = 0; j < 2; ++j) acc[i][j] = zero;

    const int sra = t >> 2;
    const int sca = (t & 3) * 16;
    const int tb  = t & 255;
    const int srb = tb >> 2;
    const int scb = (tb & 3) * 16;
    const bool isBl = (t >= 256);
    const unsigned short* pB = isBl ? &Bl[(size_t)(bn + srb) * 1024 + scb]
                                    : &Bh[(size_t)(bn + srb) * 1024 + scb];
    const float* pAf = AF32 ? &Af[(size_t)(bm + sra) * 1024 + sca] : nullptr;
    const unsigned short* pAh = AF32 ? nullptr : &Ah[(size_t)(bm + sra) * 1024 + sca];
    const unsigned short* pAl = AF32 ? nullptr : &Al[(size_t)(bm + sra) * 1024 + sca];

    u16v8 rah0, rah1, ral0, ral1, rb0, rb1;
    auto LOAD = [&](int k0) {
        if (AF32) {
            const float4 a0 = *(const float4*)(pAf + k0);
            const float4 a1 = *(const float4*)(pAf + k0 + 4);
            const float4 a2 = *(const float4*)(pAf + k0 + 8);
            const float4 a3 = *(const float4*)(pAf + k0 + 12);
            const float xs[16] = {a0.x, a0.y, a0.z, a0.w, a1.x, a1.y, a1.z, a1.w,
                                  a2.x, a2.y, a2.z, a2.w, a3.x, a3.y, a3.z, a3.w};
#pragma unroll
            for (int e = 0; e < 8; ++e) {
                unsigned short hh, ll;
                split2(xs[e], hh, ll);
                rah0[e] = hh; ral0[e] = ll;
            }
#pragma unroll
            for (int e = 0; e < 8; ++e) {
                unsigned short hh, ll;
                split2(xs[8 + e], hh, ll);
                rah1[e] = hh; ral1[e] = ll;
            }
        } else {
            rah0 = *(const u16v8*)(pAh + k0);
            rah1 = *(const u16v8*)(pAh + k0 + 8);
            ral0 = *(const u16v8*)(pAl + k0);
            ral1 = *(const u16v8*)(pAl + k0 + 8);
        }
        rb0 = *(const u16v8*)(pB + k0);
        rb1 = *(const u16v8*)(pB + k0 + 8);
    };

    LOAD(0);
    for (int k0 = 0; k0 < 1024; k0 += 64) {
        __syncthreads();
        *(u16v8*)&Ash[sra][sca]     = rah0;
        *(u16v8*)&Ash[sra][sca + 8] = rah1;
        *(u16v8*)&Asl[sra][sca]     = ral0;
        *(u16v8*)&Asl[sra][sca + 8] = ral1;
        if (isBl) {
            *(u16v8*)&Bsl[srb][scb]     = rb0;
            *(u16v8*)&Bsl[srb][scb + 8] = rb1;
        } else {
            *(u16v8*)&Bsh[srb][scb]     = rb0;
            *(u16v8*)&Bsh[srb][scb + 8] = rb1;
        }
        __syncthreads();

        if (k0 + 64 < 1024) LOAD(k0 + 64);

#pragma unroll
        for (int kk2 = 0; kk2 < 2; ++kk2) {
            const int ks = kk2 * 32 + fq * 8;
            bf16v8 fah[2], fal[2], fbh[2], fbl[2];
#pragma unroll
            for (int i = 0; i < 2; ++i) {
                fah[i] = *(const bf16v8*)&Ash[wr * 32 + i * 16 + fr][ks];
                fal[i] = *(const bf16v8*)&Asl[wr * 32 + i * 16 + fr][ks];
            }
#pragma unroll
            for (int j = 0; j < 2; ++j) {
                fbh[j] = *(const bf16v8*)&Bsh[wc * 32 + j * 16 + fr][ks];
                fbl[j] = *(const bf16v8*)&Bsl[wc * 32 + j * 16 + fr][ks];
            }
#pragma unroll
            for (int i = 0; i < 2; ++i)
#pragma unroll
                for (int j = 0; j < 2; ++j) {
                    acc[i][j] = __builtin_amdgcn_mfma_f32_16x16x32_bf16(
                        fah[i], fbh[j], acc[i][j], 0, 0, 0);
                    acc[i][j] = __builtin_amdgcn_mfma_f32_16x16x32_bf16(
                        fah[i], fbl[j], acc[i][j], 0, 0, 0);
                    acc[i][j] = __builtin_amdgcn_mfma_f32_16x16x32_bf16(
                        fal[i], fbh[j], acc[i][j], 0, 0, 0);
                }
        }
    }

    if (EPI == 3) {
        float wupj[2], wudj[2], bb[2];
#pragma unroll
        for (int j = 0; j < 2; ++j) {
            const int colL = wc * 32 + j * 16 + fr;
            wupj[j] = Wup[colL];
            wudj[j] = Wud[colL];
            bb[j]   = bias[bn + colL];
        }
        float su[2][4], sd[2][4];
#pragma unroll
        for (int i = 0; i < 2; ++i)
#pragma unroll
            for (int r = 0; r < 4; ++r) { su[i][r] = 0.f; sd[i][r] = 0.f; }
#pragma unroll
        for (int j = 0; j < 2; ++j)
#pragma unroll
            for (int i = 0; i < 2; ++i)
#pragma unroll
                for (int r = 0; r < 4; ++r) {
                    const float tv = tanhf(acc[i][j][r] + bb[j]);
                    su[i][r] = fmaf(tv, wupj[j], su[i][r]);
                    sd[i][r] = fmaf(tv, wudj[j], sd[i][r]);
                }
#pragma unroll
        for (int i = 0; i < 2; ++i)
#pragma unroll
            for (int r = 0; r < 4; ++r) {
                float a = su[i][r], d = sd[i][r];
                a += __shfl_xor(a, 1); d += __shfl_xor(d, 1);
                a += __shfl_xor(a, 2); d += __shfl_xor(d, 2);
                a += __shfl_xor(a, 4); d += __shfl_xor(d, 4);
                a += __shfl_xor(a, 8); d += __shfl_xor(d, 8);
                if (fr == 0) {
                    const int row = wr * 32 + i * 16 + fq * 4 + r;
                    PSUP[wc][row] = a;
                    PSUD[wc][row] = d;
                }
            }
        __syncthreads();
        if (t < 128) {
            const float ap = PSUP[0][t] + PSUP[1][t] + bup[0];
            const float az = PSUD[0][t] + PSUD[1][t] + bud[0];
            const float cenv = 1024.f / (1.f + expf(-ap));
            const float win  = 1024.f / (1.f + expf(-az));
            const int grow = bm + t;
            const int hd   = bn >> 6;
            const int zz   = (grow >> 10) * 16 + hd;
            const int s    = grow & 1023;
            const float al = alpha[(size_t)grow * 16 + hd];
            cenp[(size_t)zz * 1024 + s] = cenv;
            c0p[(size_t)zz * 1024 + s]  = al * 2.f / (win * win);
        }
        return;
    }

#pragma unroll
    for (int j = 0; j < 2; ++j) {
        const int col = bn + wc * 32 + j * 16 + fr;
        const float bb = bias[col];
#pragma unroll
        for (int i = 0; i < 2; ++i) {
            const int row0 = bm + wr * 32 + i * 16 + fq * 4;
            const f32v4 cv = acc[i][j];
            if (EPI == 2) {
                u16v4 h4, l4;
#pragma unroll
                for (int r = 0; r < 4; ++r) {
                    unsigned short hh, ll;
                    split2(cv[r] + bb, hh, ll);
                    h4[r] = hh; l4[r] = ll;
                }
                const size_t base =
                    ((size_t)((row0 >> 10) * 16 + (col >> 6)) * 64 + (col & 63)) * 1024
                    + (row0 & 1023);
                *(u16v4*)&Ch[base] = h4;
                *(u16v4*)&Cl[base] = l4;
            } else if (EPI == 1) {
#pragma unroll
                for (int r = 0; r < 4; ++r) {
                    unsigned short hh, ll;
                    split2(cv[r] + bb, hh, ll);
                    const size_t idx = (size_t)(row0 + r) * 1024 + col;
                    Ch[idx] = hh; Cl[idx] = ll;
                }
            } else {
#pragma unroll
                for (int r = 0; r < 4; ++r)
                    Cf[(size_t)(row0 + r) * 1024 + col] = cv[r] + bb;
            }
        }
    }
}

// ---------------------------------------------------------------------------
// attn_fused v7: pass-B P-barrier ELIMINATED via wave-private PV.
// Each wave's PV consumes only its own wc j-half of P (kk = wc), covering all
// 64 d (acco[2][4]); partial O halves combined once at the end through PH/PL
// scratch. Removes 16 block-wide vmcnt drains -> K/V prefetch now genuinely
// overlaps the PV MFMA cluster. Pass A unchanged (double-buffered, setprio).
// ---------------------------------------------------------------------------
#define M0_SHIFT 8.0f
__global__ __launch_bounds__(512, 2) void attn_fused(
    const unsigned short* __restrict__ qh, const unsigned short* __restrict__ ql,
    const unsigned short* __restrict__ kh, const unsigned short* __restrict__ kl,
    const unsigned short* __restrict__ vTh, const unsigned short* __restrict__ vTl,
    const float* __restrict__ cen, const float* __restrict__ c0,
    float* __restrict__ attn,
    unsigned short* __restrict__ oh, unsigned short* __restrict__ ol)
{
    __shared__ unsigned short KH[64][64], KL[64][64];
    __shared__ unsigned short VH[64][64], VL[64][64];
    __shared__ unsigned short PH[128][64], PL[128][64];
    __shared__ float CEN[128], C0S[128];
    __shared__ float LSUM[2][128];
    __shared__ float RINV[128];

    const int bid   = blockIdx.x;
    const int z     = ((bid >> 6) << 3) | (bid & 7);
    const int itile = (bid >> 3) & 7;
    const int i0    = itile * 128;
    const int bq    = z >> 4;
    const int hd    = z & 15;

    const int t    = threadIdx.x;
    const int lane = t & 63;
    const int wid  = t >> 6;
    const int wrp  = wid >> 1;
    const int wc   = wid & 1;
    const int fr   = lane & 15, fq = lane >> 4;

    if (t < 128) {
        CEN[t] = cen[(size_t)z * 1024 + i0 + t];
        C0S[t] = c0[(size_t)z * 1024 + i0 + t];
    }

    bf16v8 qfh_[2][2], qfl_[2][2];
#pragma unroll
    for (int i = 0; i < 2; ++i)
#pragma unroll
        for (int kk = 0; kk < 2; ++kk) {
            const size_t qa = (size_t)(bq * 1024 + i0 + wrp * 32 + i * 16 + fr) * 1024
                              + hd * 64 + kk * 32 + fq * 8;
            qfh_[i][kk] = *(const bf16v8*)&qh[qa];
            qfl_[i][kk] = *(const bf16v8*)&ql[qa];
        }

    float lsum[2][4];
#pragma unroll
    for (int i = 0; i < 2; ++i)
#pragma unroll
        for (int r = 0; r < 4; ++r) lsum[i][r] = 0.f;

    const f32v4 zero = {0.f, 0.f, 0.f, 0.f};

    const int srow = t >> 3;
    const int sseg = t & 7;
    const int ssl  = (sseg ^ (srow & 7)) * 8;
    const unsigned short* vhb = vTh + (size_t)z * 64 * 1024;
    const unsigned short* vlb = vTl + (size_t)z * 64 * 1024;

    u16v8 rkh, rkl, rvh, rvl;
    auto LOADK = [&](int j0) {
        const size_t ga = (size_t)(bq * 1024 + j0 + srow) * 1024 + hd * 64 + sseg * 8;
        rkh = *(const u16v8*)&kh[ga];
        rkl = *(const u16v8*)&kl[ga];
    };
    auto LOADV = [&](int j0) {
        const size_t va = (size_t)srow * 1024 + j0 + sseg * 8;
        rvh = *(const u16v8*)&vhb[va];
        rvl = *(const u16v8*)&vlb[va];
    };

    // ---------------- PASS A: K double-buffered, 1 barrier/tile ----------
    LOADK(0);
    for (int jt = 0; jt < 16; ++jt) {
        const int j0 = jt * 64;
        unsigned short (*KHc)[64] = (jt & 1) ? VH : KH;
        unsigned short (*KLc)[64] = (jt & 1) ? VL : KL;
        *(u16v8*)&KHc[srow][ssl] = rkh;
        *(u16v8*)&KLc[srow][ssl] = rkl;
        __syncthreads();
        if (jt < 15) LOADK(j0 + 64);

        f32v4 acc[2][2];
#pragma unroll
        for (int i = 0; i < 2; ++i)
#pragma unroll
            for (int j2 = 0; j2 < 2; ++j2) acc[i][j2] = zero;

        __builtin_amdgcn_s_setprio(1);
#pragma unroll
        for (int kk = 0; kk < 2; ++kk) {
            bf16v8 fbh[2], fbl[2];
#pragma unroll
            for (int j2 = 0; j2 < 2; ++j2) {
                const int rb = wc * 32 + j2 * 16 + fr;
                const int sb = ((kk * 4 + fq) ^ (rb & 7)) * 8;
                fbh[j2] = *(const bf16v8*)&KHc[rb][sb];
                fbl[j2] = *(const bf16v8*)&KLc[rb][sb];
            }
#pragma unroll
            for (int i = 0; i < 2; ++i)
#pragma unroll
                for (int j2 = 0; j2 < 2; ++j2) {
                    acc[i][j2] = __builtin_amdgcn_mfma_f32_16x16x32_bf16(
                        qfh_[i][kk], fbh[j2], acc[i][j2], 0, 0, 0);
                    acc[i][j2] = __builtin_amdgcn_mfma_f32_16x16x32_bf16(
                        qfh_[i][kk], fbl[j2], acc[i][j2], 0, 0, 0);
                    acc[i][j2] = __builtin_amdgcn_mfma_f32_16x16x32_bf16(
                        qfl_[i][kk], fbh[j2], acc[i][j2], 0, 0, 0);
                }
        }
        __builtin_amdgcn_s_setprio(0);

#pragma unroll
        for (int i = 0; i < 2; ++i)
#pragma unroll
            for (int r = 0; r < 4; ++r) {
                const int row = wrp * 32 + i * 16 + fq * 4 + r;
                const float cv = CEN[row], cc = C0S[row];
                float al = 0.f;
#pragma unroll
                for (int j2 = 0; j2 < 2; ++j2) {
                    const int col = wc * 32 + j2 * 16 + fr;
                    const float dd = (float)(j0 + col) - cv;
                    const float s  = acc[i][j2][r] * 0.125f - cc * dd * dd;
                    al += __expf(s - M0_SHIFT);
                }
                lsum[i][r] += al;
            }
    }

#pragma unroll
    for (int i = 0; i < 2; ++i)
#pragma unroll
        for (int r = 0; r < 4; ++r) {
            float v = lsum[i][r];
            v += __shfl_xor(v, 1);
            v += __shfl_xor(v, 2);
            v += __shfl_xor(v, 4);
            v += __shfl_xor(v, 8);
            if (fr == 0) LSUM[wc][wrp * 32 + i * 16 + fq * 4 + r] = v;
        }
    __syncthreads();
    if (t < 128) RINV[t] = 1.f / (LSUM[0][t] + LSUM[1][t]);

    // ---------------- PASS B: wave-private PV, 2 barriers/tile ----------
    f32v4 acco[2][4];
#pragma unroll
    for (int i = 0; i < 2; ++i)
#pragma unroll
        for (int j = 0; j < 4; ++j) acco[i][j] = zero;

    float* attnZ = attn + (size_t)z * 1024 * 1024;

    LOADK(0);
    LOADV(0);
    for (int jt = 0; jt < 16; ++jt) {
        const int j0 = jt * 64;
        __syncthreads();   // prev tile's PV (V reads) done; RINV ready (jt=0)
        *(u16v8*)&KH[srow][ssl] = rkh;
        *(u16v8*)&KL[srow][ssl] = rkl;
        *(u16v8*)&VH[srow][ssl] = rvh;
        *(u16v8*)&VL[srow][ssl] = rvl;
        __syncthreads();
        if (jt < 15) { LOADK(j0 + 64); LOADV(j0 + 64); }   // overlaps QK^T+PV

        f32v4 acc[2][2];
#pragma unroll
        for (int i = 0; i < 2; ++i)
#pragma unroll
            for (int j2 = 0; j2 < 2; ++j2) acc[i][j2] = zero;

        __builtin_amdgcn_s_setprio(1);
#pragma unroll
        for (int kk = 0; kk < 2; ++kk) {
            bf16v8 fbh[2], fbl[2];
#pragma unroll
            for (int j2 = 0; j2 < 2; ++j2) {
                const int rb = wc * 32 + j2 * 16 + fr;
                const int sb = ((kk * 4 + fq) ^ (rb & 7)) * 8;
                fbh[j2] = *(const bf16v8*)&KH[rb][sb];
                fbl[j2] = *(const bf16v8*)&KL[rb][sb];
            }
#pragma unroll
            for (int i = 0; i < 2; ++i)
#pragma unroll
                for (int j2 = 0; j2 < 2; ++j2) {
                    acc[i][j2] = __builtin_amdgcn_mfma_f32_16x16x32_bf16(
                        qfh_[i][kk], fbh[j2], acc[i][j2], 0, 0, 0);
                    acc[i][j2] = __builtin_amdgcn_mfma_f32_16x16x32_bf16(
                        qfh_[i][kk], fbl[j2], acc[i][j2], 0, 0, 0);
                    acc[i][j2] = __builtin_amdgcn_mfma_f32_16x16x32_bf16(
                        qfl_[i][kk], fbh[j2], acc[i][j2], 0, 0, 0);
                }
        }
        __builtin_amdgcn_s_setprio(0);

        // P = exp(s-8)*rinv: attn store + wave-private PH/PL scatter
#pragma unroll
        for (int i = 0; i < 2; ++i)
#pragma unroll
            for (int r = 0; r < 4; ++r) {
                const int row = wrp * 32 + i * 16 + fq * 4 + r;
                const float cv = CEN[row], cc = C0S[row], ri = RINV[row];
#pragma unroll
                for (int j2 = 0; j2 < 2; ++j2) {
                    const int col = wc * 32 + j2 * 16 + fr;
                    const float dd = (float)(j0 + col) - cv;
                    const float s  = acc[i][j2][r] * 0.125f - cc * dd * dd;
                    const float p  = __expf(s - M0_SHIFT) * ri;
                    attnZ[(size_t)(i0 + row) * 1024 + j0 + col] = p;
                    unsigned short hv, lv;
                    split2(p, hv, lv);
                    const int slot = ((col >> 3) ^ (row & 7)) * 8 + (col & 7);
                    PH[row][slot] = hv;
                    PL[row][slot] = lv;
                }
            }
        // NO barrier: P quadrant is wave-private (rows wrp*32.., cols wc*32..);
        // compiler orders ds_write -> ds_read via lgkmcnt.

        // PV over own j-half (kk = wc), all 64 d (jd = 0..3)
        __builtin_amdgcn_s_setprio(1);
        {
            bf16v8 pah[2], pal[2];
#pragma unroll
            for (int iq = 0; iq < 2; ++iq) {
                const int rp = wrp * 32 + iq * 16 + fr;
                const int sp = ((wc * 4 + fq) ^ (rp & 7)) * 8;
                pah[iq] = *(const bf16v8*)&PH[rp][sp];
                pal[iq] = *(const bf16v8*)&PL[rp][sp];
            }
#pragma unroll
            for (int jd = 0; jd < 4; ++jd) {
                const int rb = jd * 16 + fr;
                const int sb = ((wc * 4 + fq) ^ (rb & 7)) * 8;
                const bf16v8 vfh = *(const bf16v8*)&VH[rb][sb];
                const bf16v8 vfl = *(const bf16v8*)&VL[rb][sb];
#pragma unroll
                for (int iq = 0; iq < 2; ++iq) {
                    acco[iq][jd] = __builtin_amdgcn_mfma_f32_16x16x32_bf16(
                        pah[iq], vfh, acco[iq][jd], 0, 0, 0);
                    acco[iq][jd] = __builtin_amdgcn_mfma_f32_16x16x32_bf16(
                        pah[iq], vfl, acco[iq][jd], 0, 0, 0);
                    acco[iq][jd] = __builtin_amdgcn_mfma_f32_16x16x32_bf16(
                        pal[iq], vfh, acco[iq][jd], 0, 0, 0);
                }
            }
        }
        __builtin_amdgcn_s_setprio(0);
    }

    // ---------------- combine j-half partials, epilogue ----------------
    __syncthreads();   // all PV (and PH reads) done before scratch overwrite
    if (wc == 1) {
        float* s0 = (float*)PH;    // 4096 floats: iq=0 partials
        float* s1 = (float*)PL;    // 4096 floats: iq=1 partials
#pragma unroll
        for (int jd = 0; jd < 4; ++jd)
#pragma unroll
            for (int r = 0; r < 4; ++r) {
                const int idx = ((wrp * 4 + jd) * 4 + r) * 64 + lane;
                s0[idx] = acco[0][jd][r];
                s1[idx] = acco[1][jd][r];
            }
    }
    __syncthreads();
    if (wc == 0) {
        const float* s0 = (const float*)PH;
        const float* s1 = (const float*)PL;
#pragma unroll
        for (int jd = 0; jd < 4; ++jd) {
            const int dcol = jd * 16 + fr;
#pragma unroll
            for (int iq = 0; iq < 2; ++iq) {
                const int row0 = i0 + wrp * 32 + iq * 16 + fq * 4;
                const float* sp = (iq == 0) ? s0 : s1;
#pragma unroll
                for (int r = 0; r < 4; ++r) {
                    const float v = acco[iq][jd][r] +
                        sp[((wrp * 4 + jd) * 4 + r) * 64 + lane];
                    unsigned short hv, lv;
                    split2(v, hv, lv);
                    const size_t idx = (size_t)(bq * 1024 + row0 + r) * 1024
                                       + hd * 64 + dcol;
                    oh[idx] = hv;
                    ol[idx] = lv;
                }
            }
        }
    }
}

// ---------------------------------------------------------------------------
extern "C" void kernel_launch(void* const* d_in, const int* in_sizes, int n_in,
                              void* d_out, int out_size, void* d_ws, size_t ws_size,
                              hipStream_t stream)
{
    const float* query = (const float*)d_in[0];
    const float* key_  = (const float*)d_in[1];
    const float* value = (const float*)d_in[2];
    const float* Wq  = (const float*)d_in[3];
    const float* bq  = (const float*)d_in[4];
    const float* Wk  = (const float*)d_in[5];
    const float* bk  = (const float*)d_in[6];
    const float* Wv  = (const float*)d_in[7];
    const float* bv  = (const float*)d_in[8];
    const float* Wp  = (const float*)d_in[9];
    const float* bp  = (const float*)d_in[10];
    const float* Wup = (const float*)d_in[11];
    const float* bup = (const float*)d_in[12];
    const float* Wud = (const float*)d_in[13];
    const float* bud = (const float*)d_in[14];
    const float* Wus = (const float*)d_in[15];
    const float* bus = (const float*)d_in[16];
    const float* Wo  = (const float*)d_in[17];
    const float* bo  = (const float*)d_in[18];

    float* x_out = (float*)d_out;                         // [4096,1024]
    float* attn  = x_out + (size_t)MTOT * HIDN;           // [64,1024,1024]

    // ---- workspace layout (bytes)
    char* wsb = (char*)d_ws;
    unsigned short* qh  = (unsigned short*)(wsb);                  // 8 MB
    unsigned short* ql  = (unsigned short*)(wsb + (8u  << 20));
    unsigned short* kh  = (unsigned short*)(wsb + (16u << 20));
    unsigned short* kl  = (unsigned short*)(wsb + (24u << 20));
    unsigned short* vTh = (unsigned short*)(wsb + (32u << 20));
    unsigned short* vTl = (unsigned short*)(wsb + (40u << 20));
    unsigned short* oh  = (unsigned short*)(wsb + (48u << 20));    // 8 MB
    unsigned short* ol  = (unsigned short*)(wsb + (56u << 20));
    float* alpha_ws = (float*)(wsb + (64u << 20));                 // 256 KB
    float* cen_ws   = (float*)(wsb + (64u << 20) + (256u << 10));
    float* c0_ws    = (float*)(wsb + (64u << 20) + (512u << 10));
    // weight splits for Wq/Wk/Wv/Wp live in the (not-yet-written) attn region
    unsigned short* wh = (unsigned short*)attn;                    // 4 x 2 MB
    unsigned short* wl = wh + (size_t)4 * 1024 * 1024;             // 4 x 2 MB
    // Wo split reuses qh/ql space after attn_fused
    unsigned short* w2h = qh;
    unsigned short* w2l = ql;

    const dim3 blk(256);
    const dim3 blk512(512);
    const dim3 ggemm(HIDN / 64, MTOT / 128);   // (16, 32) = 512 blocks
    const size_t WSTEP = (size_t)1024 * 1024;

    // weight splits (Wq,Wk,Wv,Wp) batched + alpha
    split_w4<<<dim3(16, 16, 4), blk, 0, stream>>>(Wq, Wk, Wv, Wp, wh, wl);
    alpha_kernel<<<dim3(MTOT / 16), blk, 0, stream>>>(query, Wus, bus, alpha_ws);
    // q = query @ Wq + bq -> qh/ql (inline f32-A split)
    gemm_t<1, 1><<<ggemm, blk512, 0, stream>>>(
        query, nullptr, nullptr, wh, wl, bq, nullptr, qh, ql,
        nullptr, nullptr, nullptr, nullptr, nullptr, nullptr, nullptr);
    // k -> kh/kl
    gemm_t<1, 1><<<ggemm, blk512, 0, stream>>>(
        key_, nullptr, nullptr, wh + WSTEP, wl + WSTEP, bk, nullptr, kh, kl,
        nullptr, nullptr, nullptr, nullptr, nullptr, nullptr, nullptr);
    // v -> vTh/vTl (per-head transposed)
    gemm_t<1, 2><<<ggemm, blk512, 0, stream>>>(
        value, nullptr, nullptr, wh + 2 * WSTEP, wl + 2 * WSTEP, bv,
        nullptr, vTh, vTl,
        nullptr, nullptr, nullptr, nullptr, nullptr, nullptr, nullptr);
    // p = q @ Wp + bp with fused posparam -> cen/c0 (p never materialized)
    gemm_t<0, 3><<<ggemm, blk512, 0, stream>>>(
        nullptr, qh, ql, wh + 3 * WSTEP, wl + 3 * WSTEP, bp, nullptr,
        nullptr, nullptr,
        Wup, Wud, bup, bud, alpha_ws, cen_ws, c0_ws);
    // fused scores + softmax + attn-write + PV
    attn_fused<<<dim3(512), blk512, 0, stream>>>(
        qh, ql, kh, kl, vTh, vTl, cen_ws, c0_ws, attn, oh, ol);
    // Wo split (into dead qh/ql region), then x = o @ Wo + bo
    split_w4<<<dim3(16, 16, 1), blk, 0, stream>>>(Wo, Wo, Wo, Wo, w2h, w2l);
    gemm_t<0, 0><<<ggemm, blk512, 0, stream>>>(
        nullptr, oh, ol, w2h, w2l, bo, x_out, nullptr, nullptr,
        nullptr, nullptr, nullptr, nullptr, nullptr, nullptr, nullptr);
}